// Round 1
// baseline (2113.754 us; speedup 1.0000x reference)
//
#include <hip/hip_runtime.h>

typedef unsigned short u16;
typedef short s16x8 __attribute__((ext_vector_type(8)));
typedef u16 u16x8 __attribute__((ext_vector_type(8)));
typedef float f32x4 __attribute__((ext_vector_type(4)));

// ---------- helpers ----------
__device__ inline float bf2f(u16 u) {
    union { unsigned int i; float f; } w; w.i = ((unsigned int)u) << 16; return w.f;
}
__device__ inline u16 f2bf(float f) {
    union { float f; unsigned int i; } w; w.f = f;
    unsigned int u = w.i;
    u += 0x7fffu + ((u >> 16) & 1u);
    return (u16)(u >> 16);
}

// ---------- weight transpose + bf16 convert: dst[n*K+k] = src[k*N+n] ----------
__global__ void wtransk(const float* __restrict__ src, u16* __restrict__ dst, int K, int N) {
    size_t idx = (size_t)blockIdx.x * 256 + threadIdx.x;
    if (idx >= (size_t)K * N) return;
    int n = (int)(idx / K), k = (int)(idx % K);
    dst[idx] = f2bf(src[(size_t)k * N + n]);
}

// ---------- plain f32 -> bf16 convert ----------
__global__ void cvtk(const float* __restrict__ src, u16* __restrict__ dst, int n) {
    int i = blockIdx.x * 256 + threadIdx.x;
    if (i < n) dst[i] = f2bf(src[i]);
}

// ---------- GEMM: C[M,N] = A[M,K](bf16) @ WT[N,K](bf16)^T ----------
// EPI 0: v += bias[col]; fout[row*ostride+col]=v; bout[same]=bf16(v)      (patch)
// EPI 1: bout[row*ostride + ocoloff + col] = bf16(v)                      (in_proj / out_proj)
// EPI 2: xv = fout[row*768+col] + v*lsv[col]; fout=xv; bout=bf16(xv)      (bi + residual)
template<int EPI>
__global__ __launch_bounds__(256)
void gemm_k(const u16* __restrict__ A, const u16* __restrict__ WT,
            int M, int N, int K,
            float* __restrict__ fout, u16* __restrict__ bout,
            const float* __restrict__ bias, const float* __restrict__ lsv,
            int ostride, int ocoloff)
{
    const int tid  = threadIdx.x;
    const int lane = tid & 63;
    const int wave = tid >> 6;
    const int wm = wave >> 1, wn = wave & 1;
    const int r16 = lane & 15;
    const int ks  = (lane >> 4) * 8;
    const int mb  = blockIdx.y * 64 + wm * 32;
    const int nb  = blockIdx.x * 128 + wn * 64;

    f32x4 acc[2][4];
#pragma unroll
    for (int mi = 0; mi < 2; mi++)
#pragma unroll
        for (int ni = 0; ni < 4; ni++)
            acc[mi][ni] = (f32x4){0.f, 0.f, 0.f, 0.f};

    const u16* a0p = A + (size_t)(mb + r16) * K + ks;
    const u16* a1p = a0p + (size_t)16 * K;

    int ncol[4]; bool nok[4]; const u16* bpp[4];
#pragma unroll
    for (int ni = 0; ni < 4; ni++) {
        ncol[ni] = nb + ni * 16 + r16;
        nok[ni]  = ncol[ni] < N;
        bpp[ni]  = WT + (size_t)(nok[ni] ? ncol[ni] : 0) * K + ks;
    }
    const s16x8 bz = {0,0,0,0,0,0,0,0};

    for (int k0 = 0; k0 < K; k0 += 32) {
        s16x8 a0 = *(const s16x8*)(a0p + k0);
        s16x8 a1 = *(const s16x8*)(a1p + k0);
#pragma unroll
        for (int ni = 0; ni < 4; ni++) {
            s16x8 bf = nok[ni] ? *(const s16x8*)(bpp[ni] + k0) : bz;
            acc[0][ni] = __builtin_amdgcn_mfma_f32_16x16x32_bf16(a0, bf, acc[0][ni], 0, 0, 0);
            acc[1][ni] = __builtin_amdgcn_mfma_f32_16x16x32_bf16(a1, bf, acc[1][ni], 0, 0, 0);
        }
    }

    const int srow = mb + (lane >> 4) * 4;
#pragma unroll
    for (int mi = 0; mi < 2; mi++) {
#pragma unroll
        for (int ni = 0; ni < 4; ni++) {
            if (ncol[ni] < N) {
#pragma unroll
                for (int j = 0; j < 4; j++) {
                    int row = srow + mi * 16 + j;
                    int col = ncol[ni];
                    float v = acc[mi][ni][j];
                    if (EPI == 0) {
                        v += bias[col];
                        size_t o = (size_t)row * ostride + col;
                        fout[o] = v; bout[o] = f2bf(v);
                    } else if (EPI == 1) {
                        bout[(size_t)row * ostride + ocoloff + col] = f2bf(v);
                    } else {
                        size_t o = (size_t)row * 768 + col;
                        float xv = fout[o] + v * lsv[col];
                        fout[o] = xv; bout[o] = f2bf(xv);
                    }
                }
            }
        }
    }
}

// ---------- softplus(dt_raw + dt_bias) ----------
__global__ void dtk(const u16* __restrict__ zx0, const u16* __restrict__ zx1,
                    float* __restrict__ dt0, float* __restrict__ dt1,
                    const float* __restrict__ dtb)
{
    int idx = blockIdx.x * 256 + threadIdx.x;
    if (idx >= 2 * 4096 * 24) return;
    int dir = idx / (4096 * 24);
    int r   = idx % (4096 * 24);
    int row = r / 24, h = r % 24;
    const u16* zx = dir ? zx1 : zx0;
    float* dtp = dir ? dt1 : dt0;
    float raw = bf2f(zx[(size_t)row * 3128 + 3104 + h]) + dtb[dir * 24 + h];
    dtp[row * 24 + h] = raw > 20.f ? raw : log1pf(__expf(raw));
}

// ---------- depthwise causal conv (dir 0) / anti-causal (dir 1) + bias + silu ----------
__global__ void convk(const u16* __restrict__ zx0, const u16* __restrict__ zx1,
                      u16* __restrict__ xc0, u16* __restrict__ xc1,
                      const float* __restrict__ cw, const float* __restrict__ cb)
{
    int dir  = blockIdx.y;
    int flat = blockIdx.x * 256 + threadIdx.x;   // 0 .. 4096*1568-1
    int c    = flat % 1568;
    int row  = flat / 1568;
    int l    = row & 2047;
    const u16* zx = dir ? zx1 : zx0;
    u16* xc = dir ? xc1 : xc0;
    float acc = cb[dir * 1568 + c];
    const float* w = cw + ((size_t)dir * 1568 + c) * 4;
#pragma unroll
    for (int k = 0; k < 4; k++) {
        int ll = dir ? (l + 3 - k) : (l - 3 + k);
        if (ll >= 0 && ll < 2048)
            acc += bf2f(zx[(size_t)(row + (ll - l)) * 3128 + 1536 + c]) * w[k];
    }
    acc = acc / (1.f + __expf(-acc));
    xc[(size_t)row * 1568 + c] = f2bf(acc);
}

// ---------- sequential SSM scan: one wave per (dir, b, head) ----------
__global__ __launch_bounds__(64)
void scank(const u16* __restrict__ xc0, const u16* __restrict__ xc1,
           const float* __restrict__ dt0, const float* __restrict__ dt1,
           const float* __restrict__ Alog, const float* __restrict__ Dhp,
           u16* __restrict__ y0, u16* __restrict__ y1)
{
    int bid = blockIdx.x;
    int dir = bid / 48;
    int r   = bid % 48;
    int b   = r / 24;
    int h   = r % 24;
    const u16* xc  = dir ? xc1 : xc0;
    const float* dtp = dir ? dt1 : dt0;
    u16* yp = dir ? y1 : y0;
    const float Av = -__expf(Alog[dir * 24 + h]);
    const float Dv = Dhp[dir * 24 + h];
    const int p = threadIdx.x;   // 0..63 = headdim index

    __shared__ u16 xs[2][64][64];
    __shared__ u16 bcs[2][64][32];
    __shared__ float dts[2][64];

    float hst[16];
#pragma unroll
    for (int n = 0; n < 16; n++) hst[n] = 0.f;

    u16x8 rx[8]; u16x8 rbc[4]; float rdt;

    auto load_chunk = [&](int c) {
        int l = dir ? (2047 - (c * 64 + p)) : (c * 64 + p);
        size_t row = (size_t)b * 2048 + l;
        const u16* px = xc + row * 1568 + h * 64;
#pragma unroll
        for (int j = 0; j < 8; j++) rx[j] = *(const u16x8*)(px + j * 8);
        const u16* pbc = xc + row * 1568 + 1536;
#pragma unroll
        for (int j = 0; j < 4; j++) rbc[j] = *(const u16x8*)(pbc + j * 8);
        rdt = dtp[row * 24 + h];
    };
    auto store_chunk = [&](int buf) {
#pragma unroll
        for (int j = 0; j < 8; j++) *(u16x8*)&xs[buf][p][j * 8] = rx[j];
#pragma unroll
        for (int j = 0; j < 4; j++) *(u16x8*)&bcs[buf][p][j * 8] = rbc[j];
        dts[buf][p] = rdt;
    };
    auto compute_chunk = [&](int buf, int c) {
        for (int t = 0; t < 64; t++) {
            float dtv = dts[buf][t];
            float dA  = __expf(dtv * Av);
            float xv  = bf2f(xs[buf][t][p]);
            float t1  = dtv * xv;
            float acc = 0.f;
#pragma unroll
            for (int n = 0; n < 16; n++) {
                float Bn = bf2f(bcs[buf][t][n]);
                float Cn = bf2f(bcs[buf][t][16 + n]);
                hst[n] = hst[n] * dA + t1 * Bn;
                acc += hst[n] * Cn;
            }
            int l = dir ? (2047 - (c * 64 + t)) : (c * 64 + t);
            size_t row = (size_t)b * 2048 + l;
            yp[row * 1536 + h * 64 + p] = f2bf(acc + Dv * xv);
        }
    };

    load_chunk(0);
    store_chunk(0);
    __builtin_amdgcn_s_waitcnt(0); // drain lgkm before first reads (single wave)
    for (int c = 0; c < 32; c++) {
        int buf = c & 1;
        if (c + 1 < 32) load_chunk(c + 1);
        compute_chunk(buf, c);
        if (c + 1 < 32) store_chunk(buf ^ 1);
    }
}

// ---------- gating + RMSnorm (in-place on y, output bf16) ----------
__global__ __launch_bounds__(256)
void gatek(const u16* __restrict__ zx0, const u16* __restrict__ zx1,
           u16* __restrict__ y0, u16* __restrict__ y1,
           const float* __restrict__ nw)
{
    int row = blockIdx.x, dir = blockIdx.y;
    const u16* zx = (dir ? zx1 : zx0) + (size_t)row * 3128;
    u16* y = (dir ? y1 : y0) + (size_t)row * 1536;
    const float* nwp = nw + dir * 1536;
    int tid = threadIdx.x;
    float g[6]; float s = 0.f;
#pragma unroll
    for (int j = 0; j < 6; j++) {
        int c = j * 256 + tid;
        float z  = bf2f(zx[c]);
        float yv = bf2f(y[c]);
        float gv = yv * z / (1.f + __expf(-z));
        g[j] = gv; s += gv * gv;
    }
    __shared__ float red[4];
    for (int o = 32; o; o >>= 1) s += __shfl_down(s, o, 64);
    if ((tid & 63) == 0) red[tid >> 6] = s;
    __syncthreads();
    s = red[0] + red[1] + red[2] + red[3];
    float sc = rsqrtf(s * (1.f / 1536.f) + 1e-5f);
#pragma unroll
    for (int j = 0; j < 6; j++) {
        int c = j * 256 + tid;
        y[c] = f2bf(g[j] * sc * nwp[c]);
    }
}

// ---------- final RMS norm ----------
__global__ __launch_bounds__(256)
void finalk(const float* __restrict__ x, const float* __restrict__ fw, float* __restrict__ out)
{
    int row = blockIdx.x; int tid = threadIdx.x;
    const float* xr = x + (size_t)row * 768;
    float v[3]; float s = 0.f;
#pragma unroll
    for (int j = 0; j < 3; j++) {
        int c = j * 256 + tid;
        v[j] = xr[c]; s += v[j] * v[j];
    }
    __shared__ float red[4];
    for (int o = 32; o; o >>= 1) s += __shfl_down(s, o, 64);
    if ((tid & 63) == 0) red[tid >> 6] = s;
    __syncthreads();
    s = red[0] + red[1] + red[2] + red[3];
    float sc = rsqrtf(s * (1.f / 768.f) + 1e-6f);
#pragma unroll
    for (int j = 0; j < 3; j++) {
        int c = j * 256 + tid;
        out[(size_t)row * 768 + c] = v[j] * sc * (1.f + fw[c]);
    }
}

// ---------- host ----------
extern "C" void kernel_launch(void* const* d_in, const int* in_sizes, int n_in,
                              void* d_out, int out_size, void* d_ws, size_t ws_size,
                              hipStream_t stream)
{
    const float* pe      = (const float*)d_in[0];
    const float* Wp      = (const float*)d_in[1];
    const float* bp      = (const float*)d_in[2];
    const float* in_w    = (const float*)d_in[3];
    const float* conv_w  = (const float*)d_in[4];
    const float* conv_b  = (const float*)d_in[5];
    const float* dt_bias = (const float*)d_in[6];
    const float* A_log   = (const float*)d_in[7];
    const float* Dh      = (const float*)d_in[8];
    const float* norm_w  = (const float*)d_in[9];
    const float* out_w   = (const float*)d_in[10];
    const float* bi_w    = (const float*)d_in[11];
    const float* ls      = (const float*)d_in[12];
    const float* fin_w   = (const float*)d_in[13];

    char* wp = (char*)d_ws;
    auto alloc = [&](size_t bytes) {
        char* r = wp; wp += (bytes + 255) & ~(size_t)255; return r;
    };
    u16*   WpT   = (u16*)  alloc((size_t)768 * 256 * 2);
    u16*   inWT  = (u16*)  alloc((size_t)4 * 3128 * 768 * 2);
    u16*   outWT = (u16*)  alloc((size_t)4 * 768 * 1536 * 2);
    u16*   biWT  = (u16*)  alloc((size_t)2 * 768 * 1536 * 2);
    u16*   peB   = (u16*)  alloc((size_t)4096 * 256 * 2);
    float* x     = (float*)alloc((size_t)4096 * 768 * 4);
    u16*   xb    = (u16*)  alloc((size_t)4096 * 768 * 2);
    u16*   zx0   = (u16*)  alloc((size_t)4096 * 3128 * 2);
    u16*   zx1   = (u16*)  alloc((size_t)4096 * 3128 * 2);
    float* dt0   = (float*)alloc((size_t)4096 * 24 * 4);
    float* dt1   = (float*)alloc((size_t)4096 * 24 * 4);
    u16*   xc0   = (u16*)  alloc((size_t)4096 * 1568 * 2);
    u16*   xc1   = (u16*)  alloc((size_t)4096 * 1568 * 2);
    u16*   y0    = (u16*)  alloc((size_t)4096 * 1536 * 2);
    u16*   y1    = (u16*)  alloc((size_t)4096 * 1536 * 2);
    u16*   hcat  = (u16*)  alloc((size_t)4096 * 1536 * 2);

    // weights -> bf16 transposed
    wtransk<<<768, 256, 0, stream>>>(Wp, WpT, 256, 768);
    for (int s = 0; s < 4; s++)
        wtransk<<<(2402304 + 255) / 256, 256, 0, stream>>>(
            in_w + (size_t)s * 768 * 3128, inWT + (size_t)s * 3128 * 768, 768, 3128);
    for (int s = 0; s < 4; s++)
        wtransk<<<(1179648 + 255) / 256, 256, 0, stream>>>(
            out_w + (size_t)s * 1536 * 768, outWT + (size_t)s * 768 * 1536, 1536, 768);
    for (int s = 0; s < 2; s++)
        wtransk<<<(1179648 + 255) / 256, 256, 0, stream>>>(
            bi_w + (size_t)s * 1536 * 768, biWT + (size_t)s * 768 * 1536, 1536, 768);
    cvtk<<<4096, 256, 0, stream>>>(pe, peB, 4096 * 256);

    // patch embedding GEMM: x = peB @ Wp + bp
    gemm_k<0><<<dim3(6, 64), 256, 0, stream>>>(peB, WpT, 4096, 768, 256,
                                               x, xb, bp, nullptr, 768, 0);

    for (int i = 0; i < 2; i++) {
        // in_proj both dirs
        for (int d = 0; d < 2; d++)
            gemm_k<1><<<dim3(25, 64), 256, 0, stream>>>(
                xb, inWT + (size_t)(i * 2 + d) * 3128 * 768, 4096, 3128, 768,
                nullptr, d ? zx1 : zx0, nullptr, nullptr, 3128, 0);
        dtk<<<(2 * 4096 * 24 + 255) / 256, 256, 0, stream>>>(zx0, zx1, dt0, dt1, dt_bias + i * 48);
        convk<<<dim3(25088, 2), 256, 0, stream>>>(zx0, zx1, xc0, xc1,
                                                  conv_w + (size_t)i * 2 * 1568 * 4,
                                                  conv_b + (size_t)i * 2 * 1568);
        scank<<<96, 64, 0, stream>>>(xc0, xc1, dt0, dt1, A_log + i * 48, Dh + i * 48, y0, y1);
        gatek<<<dim3(4096, 2), 256, 0, stream>>>(zx0, zx1, y0, y1, norm_w + (size_t)i * 2 * 1536);
        for (int d = 0; d < 2; d++)
            gemm_k<1><<<dim3(6, 64), 256, 0, stream>>>(
                d ? y1 : y0, outWT + (size_t)(i * 2 + d) * 768 * 1536, 4096, 768, 1536,
                nullptr, hcat, nullptr, nullptr, 1536, d * 768);
        gemm_k<2><<<dim3(6, 64), 256, 0, stream>>>(
            hcat, biWT + (size_t)i * 768 * 1536, 4096, 768, 1536,
            x, xb, nullptr, ls + i * 768, 768, 0);
    }

    finalk<<<4096, 256, 0, stream>>>(x, fin_w, (float*)d_out);
}

// Round 2
// 1290.008 us; speedup vs baseline: 1.6386x; 1.6386x over previous
//
#include <hip/hip_runtime.h>

typedef unsigned short u16;
typedef short s16x8 __attribute__((ext_vector_type(8)));
typedef u16 u16x8 __attribute__((ext_vector_type(8)));
typedef float f32x4 __attribute__((ext_vector_type(4)));

// ---------- helpers ----------
__device__ inline float bf2f(u16 u) {
    union { unsigned int i; float f; } w; w.i = ((unsigned int)u) << 16; return w.f;
}
__device__ inline u16 f2bf(float f) {
    union { float f; unsigned int i; } w; w.f = f;
    unsigned int u = w.i;
    u += 0x7fffu + ((u >> 16) & 1u);
    return (u16)(u >> 16);
}

// ---------- weight transpose + bf16 convert: dst[n*K+k] = src[k*N+n] ----------
__global__ void wtransk(const float* __restrict__ src, u16* __restrict__ dst, int K, int N) {
    size_t idx = (size_t)blockIdx.x * 256 + threadIdx.x;
    if (idx >= (size_t)K * N) return;
    int n = (int)(idx / K), k = (int)(idx % K);
    dst[idx] = f2bf(src[(size_t)k * N + n]);
}

// ---------- plain f32 -> bf16 convert ----------
__global__ void cvtk(const float* __restrict__ src, u16* __restrict__ dst, int n) {
    int i = blockIdx.x * 256 + threadIdx.x;
    if (i < n) dst[i] = f2bf(src[i]);
}

// ---------- GEMM: C[M,N] = A[M,K](bf16) @ WT[N,K](bf16)^T ----------
template<int EPI>
__global__ __launch_bounds__(256)
void gemm_k(const u16* __restrict__ A, const u16* __restrict__ WT,
            int M, int N, int K,
            float* __restrict__ fout, u16* __restrict__ bout,
            const float* __restrict__ bias, const float* __restrict__ lsv,
            int ostride, int ocoloff)
{
    const int tid  = threadIdx.x;
    const int lane = tid & 63;
    const int wave = tid >> 6;
    const int wm = wave >> 1, wn = wave & 1;
    const int r16 = lane & 15;
    const int ks  = (lane >> 4) * 8;
    const int mb  = blockIdx.y * 64 + wm * 32;
    const int nb  = blockIdx.x * 128 + wn * 64;

    f32x4 acc[2][4];
#pragma unroll
    for (int mi = 0; mi < 2; mi++)
#pragma unroll
        for (int ni = 0; ni < 4; ni++)
            acc[mi][ni] = (f32x4){0.f, 0.f, 0.f, 0.f};

    const u16* a0p = A + (size_t)(mb + r16) * K + ks;
    const u16* a1p = a0p + (size_t)16 * K;

    int ncol[4]; bool nok[4]; const u16* bpp[4];
#pragma unroll
    for (int ni = 0; ni < 4; ni++) {
        ncol[ni] = nb + ni * 16 + r16;
        nok[ni]  = ncol[ni] < N;
        bpp[ni]  = WT + (size_t)(nok[ni] ? ncol[ni] : 0) * K + ks;
    }
    const s16x8 bz = {0,0,0,0,0,0,0,0};

    for (int k0 = 0; k0 < K; k0 += 32) {
        s16x8 a0 = *(const s16x8*)(a0p + k0);
        s16x8 a1 = *(const s16x8*)(a1p + k0);
#pragma unroll
        for (int ni = 0; ni < 4; ni++) {
            s16x8 bf = nok[ni] ? *(const s16x8*)(bpp[ni] + k0) : bz;
            acc[0][ni] = __builtin_amdgcn_mfma_f32_16x16x32_bf16(a0, bf, acc[0][ni], 0, 0, 0);
            acc[1][ni] = __builtin_amdgcn_mfma_f32_16x16x32_bf16(a1, bf, acc[1][ni], 0, 0, 0);
        }
    }

    const int srow = mb + (lane >> 4) * 4;
#pragma unroll
    for (int mi = 0; mi < 2; mi++) {
#pragma unroll
        for (int ni = 0; ni < 4; ni++) {
            if (ncol[ni] < N) {
#pragma unroll
                for (int j = 0; j < 4; j++) {
                    int row = srow + mi * 16 + j;
                    int col = ncol[ni];
                    float v = acc[mi][ni][j];
                    if (EPI == 0) {
                        v += bias[col];
                        size_t o = (size_t)row * ostride + col;
                        fout[o] = v; bout[o] = f2bf(v);
                    } else if (EPI == 1) {
                        bout[(size_t)row * ostride + ocoloff + col] = f2bf(v);
                    } else {
                        size_t o = (size_t)row * 768 + col;
                        float xv = fout[o] + v * lsv[col];
                        fout[o] = xv; bout[o] = f2bf(xv);
                    }
                }
            }
        }
    }
}

// ---------- softplus(dt_raw + dt_bias) ----------
__global__ void dtk(const u16* __restrict__ zx0, const u16* __restrict__ zx1,
                    float* __restrict__ dt0, float* __restrict__ dt1,
                    const float* __restrict__ dtb)
{
    int idx = blockIdx.x * 256 + threadIdx.x;
    if (idx >= 2 * 4096 * 24) return;
    int dir = idx / (4096 * 24);
    int r   = idx % (4096 * 24);
    int row = r / 24, h = r % 24;
    const u16* zx = dir ? zx1 : zx0;
    float* dtp = dir ? dt1 : dt0;
    float raw = bf2f(zx[(size_t)row * 3128 + 3104 + h]) + dtb[dir * 24 + h];
    dtp[row * 24 + h] = raw > 20.f ? raw : log1pf(__expf(raw));
}

// ---------- depthwise causal conv (dir 0) / anti-causal (dir 1) + bias + silu ----------
__global__ void convk(const u16* __restrict__ zx0, const u16* __restrict__ zx1,
                      u16* __restrict__ xc0, u16* __restrict__ xc1,
                      const float* __restrict__ cw, const float* __restrict__ cb)
{
    int dir  = blockIdx.y;
    int flat = blockIdx.x * 256 + threadIdx.x;
    int c    = flat % 1568;
    int row  = flat / 1568;
    int l    = row & 2047;
    const u16* zx = dir ? zx1 : zx0;
    u16* xc = dir ? xc1 : xc0;
    float acc = cb[dir * 1568 + c];
    const float* w = cw + ((size_t)dir * 1568 + c) * 4;
#pragma unroll
    for (int k = 0; k < 4; k++) {
        int ll = dir ? (l + 3 - k) : (l - 3 + k);
        if (ll >= 0 && ll < 2048)
            acc += bf2f(zx[(size_t)(row + (ll - l)) * 3128 + 1536 + c]) * w[k];
    }
    acc = acc / (1.f + __expf(-acc));
    xc[(size_t)row * 1568 + c] = f2bf(acc);
}

// ---------- chunked scan pass 1: intra-chunk (MFMA) + local chunk states ----------
// grid (32 chunks, 48 b*h, 2 dir), 256 threads
__global__ __launch_bounds__(256)
void scan1k(const u16* __restrict__ xc0, const u16* __restrict__ xc1,
            const float* __restrict__ dt0, const float* __restrict__ dt1,
            const float* __restrict__ Alog, const float* __restrict__ Dhp,
            u16* __restrict__ y0, u16* __restrict__ y1,
            float* __restrict__ states, float* __restrict__ decays)
{
    const int c   = blockIdx.x;
    const int bh  = blockIdx.y;
    const int dir = blockIdx.z;
    const int b = bh / 24, h = bh % 24;
    const u16* xc    = dir ? xc1 : xc0;
    const float* dtp = dir ? dt1 : dt0;
    u16* yp = dir ? y1 : y0;
    const float Av = -__expf(Alog[dir * 24 + h]);
    const float Dv = Dhp[dir * 24 + h];
    const int inst = (dir * 2 + b) * 24 + h;

    const int tid  = threadIdx.x;
    const int lane = tid & 63;
    const int wave = tid >> 6;
    const int r16  = lane & 15;
    const int ks   = (lane >> 4) * 8;

    // padded LDS (rows 16B-aligned, not 128B-stride) to dodge bank conflicts
    __shared__ u16 xT[64][72];    // [p][s]
    __shared__ u16 Gs[64][72];    // [t][s]  (bf16 G, D folded into diagonal)
    __shared__ u16 Bs[64][40];    // [s][n]  n padded 16..31 = 0
    __shared__ u16 Cs[64][40];    // [t][n]  padded
    __shared__ u16 SBT[16][72];   // [n][s]  decay-scaled B^T
    __shared__ float dts[64], cds[64];

    auto rowof = [&](int t) -> size_t {
        int i = c * 64 + t;
        int l = dir ? (2047 - i) : i;
        return (size_t)b * 2048 + l;
    };

    // ---- load x -> xT (transposed) ----
    {
        int tr = tid >> 2;           // t
        int pg = tid & 3;            // 16-wide p group
        size_t row = rowof(tr);
        const u16* px = xc + row * 1568 + h * 64 + pg * 16;
        u16x8 v0 = *(const u16x8*)px;
        u16x8 v1 = *(const u16x8*)(px + 8);
#pragma unroll
        for (int j = 0; j < 8; j++) xT[pg * 16 + j][tr] = v0[j];
#pragma unroll
        for (int j = 0; j < 8; j++) xT[pg * 16 + 8 + j][tr] = v1[j];
    }
    // ---- load B, C (+ zero pad) ----
    {
        int t = tid & 63;
        int which = tid >> 6;
        const u16x8 z = {0,0,0,0,0,0,0,0};
        if (which == 0) {
            size_t row = rowof(t);
            const u16* pb = xc + row * 1568 + 1536;
            *(u16x8*)&Bs[t][0] = *(const u16x8*)pb;
            *(u16x8*)&Bs[t][8] = *(const u16x8*)(pb + 8);
        } else if (which == 1) {
            size_t row = rowof(t);
            const u16* pb = xc + row * 1568 + 1552;
            *(u16x8*)&Cs[t][0] = *(const u16x8*)pb;
            *(u16x8*)&Cs[t][8] = *(const u16x8*)(pb + 8);
        } else if (which == 2) {
            *(u16x8*)&Bs[t][16] = z; *(u16x8*)&Bs[t][24] = z;
        } else {
            *(u16x8*)&Cs[t][16] = z; *(u16x8*)&Cs[t][24] = z;
        }
    }
    // ---- dt + inclusive cumsum (wave 0) ----
    if (tid < 64) {
        float v = dtp[rowof(tid) * 24 + h];
        dts[tid] = v;
        float s = v;
#pragma unroll
        for (int o = 1; o < 64; o <<= 1) {
            float nvl = __shfl_up(s, o, 64);
            if (lane >= o) s += nvl;
        }
        cds[tid] = s;
    }
    __syncthreads();

    // ---- Gram S = C B^T (MFMA) -> mask/decay-scale -> G (bf16) ----
    {
        const s16x8 af = *(const s16x8*)&Cs[wave * 16 + r16][ks];
#pragma unroll
        for (int st = 0; st < 4; st++) {
            const s16x8 bf = *(const s16x8*)&Bs[st * 16 + r16][ks];
            f32x4 acc = {0.f, 0.f, 0.f, 0.f};
            acc = __builtin_amdgcn_mfma_f32_16x16x32_bf16(af, bf, acc, 0, 0, 0);
            int s = st * 16 + (lane & 15);
            int tbase = wave * 16 + (lane >> 4) * 4;
            float cs = cds[s], dtv = dts[s];
#pragma unroll
            for (int j = 0; j < 4; j++) {
                int t = tbase + j;
                float g = 0.f;
                if (s <= t) {
                    g = acc[j] * dtv * __expf(Av * (cds[t] - cs));
                    if (s == t) g += Dv;   // fold D-term into diagonal
                }
                Gs[t][s] = f2bf(g);
            }
        }
    }
    // ---- decay-scaled B^T for local state ----
    {
        float cdT = cds[63];
        int s = tid & 63;
        float sc = __expf(Av * (cdT - cds[s])) * dts[s];
#pragma unroll
        for (int it = 0; it < 4; it++) {
            int n = (tid >> 6) + it * 4;
            SBT[n][s] = f2bf(sc * bf2f(Bs[s][n]));
        }
    }
    __syncthreads();

    // ---- y_local = G @ x  (t-tile = wave) ----
    {
#pragma unroll
        for (int pt = 0; pt < 4; pt++) {
            f32x4 acc = {0.f, 0.f, 0.f, 0.f};
#pragma unroll
            for (int kk = 0; kk < 2; kk++) {
                s16x8 af = *(const s16x8*)&Gs[wave * 16 + r16][kk * 32 + ks];
                s16x8 bf = *(const s16x8*)&xT[pt * 16 + r16][kk * 32 + ks];
                acc = __builtin_amdgcn_mfma_f32_16x16x32_bf16(af, bf, acc, 0, 0, 0);
            }
            int p = pt * 16 + (lane & 15);
            int tbase = wave * 16 + (lane >> 4) * 4;
#pragma unroll
            for (int j = 0; j < 4; j++) {
                size_t row = rowof(tbase + j);
                yp[row * 1536 + h * 64 + p] = f2bf(acc[j]);
            }
        }
    }
    // ---- local chunk state L = x^T @ SB  (p-tile = wave) ----
    {
        f32x4 acc = {0.f, 0.f, 0.f, 0.f};
#pragma unroll
        for (int kk = 0; kk < 2; kk++) {
            s16x8 af = *(const s16x8*)&xT[wave * 16 + r16][kk * 32 + ks];
            s16x8 bf = *(const s16x8*)&SBT[r16][kk * 32 + ks];
            acc = __builtin_amdgcn_mfma_f32_16x16x32_bf16(af, bf, acc, 0, 0, 0);
        }
        int n = lane & 15;
        int pbase = wave * 16 + (lane >> 4) * 4;
        float* st = states + ((size_t)inst * 32 + c) * 1024;
#pragma unroll
        for (int j = 0; j < 4; j++) st[(pbase + j) * 16 + n] = acc[j];
        if (tid == 0) decays[inst * 32 + c] = __expf(Av * cds[63]);
    }
}

// ---------- chunked scan pass 2: cross-chunk recurrence (in-place: L -> h_start) ----------
__global__ __launch_bounds__(256)
void scan2k(float* __restrict__ states, const float* __restrict__ decays)
{
    int inst = blockIdx.x;
    int tid = threadIdx.x;
    float* base = states + (size_t)inst * 32 * 1024 + tid * 4;
    const float* dec = decays + inst * 32;
    f32x4 hрег = {0.f, 0.f, 0.f, 0.f};
    f32x4 L = *(f32x4*)base;
    for (int cc = 0; cc < 32; cc++) {
        f32x4 Lnext;
        if (cc + 1 < 32) Lnext = *(f32x4*)(base + (cc + 1) * 1024);
        *(f32x4*)(base + cc * 1024) = hрег;   // h at chunk start (overwrites L_cc)
        float d = dec[cc];
        hрег = hрег * d + L;
        L = Lnext;
    }
}

// ---------- chunked scan pass 3: y += C_t . (exp(A cd_t) h_start) ----------
// grid (31 chunks [1..31], 48 b*h, 2 dir), 256 threads
__global__ __launch_bounds__(256)
void scan3k(const float* __restrict__ states,
            const u16* __restrict__ xc0, const u16* __restrict__ xc1,
            const float* __restrict__ dt0, const float* __restrict__ dt1,
            const float* __restrict__ Alog,
            u16* __restrict__ y0, u16* __restrict__ y1)
{
    const int c   = blockIdx.x + 1;
    const int bh  = blockIdx.y;
    const int dir = blockIdx.z;
    const int b = bh / 24, h = bh % 24;
    const u16* xc    = dir ? xc1 : xc0;
    const float* dtp = dir ? dt1 : dt0;
    u16* yp = dir ? y1 : y0;
    const float Av = -__expf(Alog[dir * 24 + h]);
    const int inst = (dir * 2 + b) * 24 + h;
    const int tid = threadIdx.x;

    __shared__ float hs[64][20];   // [p][n] padded
    __shared__ u16 Cs3[64][16];
    __shared__ float ets[64];

    auto rowof = [&](int t) -> size_t {
        int i = c * 64 + t;
        int l = dir ? (2047 - i) : i;
        return (size_t)b * 2048 + l;
    };

    {
        const float* sp = states + ((size_t)inst * 32 + c) * 1024 + tid * 4;
        f32x4 v = *(const f32x4*)sp;
        int e = tid * 4;
        int p = e >> 4, n = e & 15;
        hs[p][n] = v[0]; hs[p][n+1] = v[1]; hs[p][n+2] = v[2]; hs[p][n+3] = v[3];
    }
    if (tid < 64) {
        size_t row = rowof(tid);
        const u16* pc = xc + row * 1568 + 1552;
        *(u16x8*)&Cs3[tid][0] = *(const u16x8*)pc;
        *(u16x8*)&Cs3[tid][8] = *(const u16x8*)(pc + 8);
        float v = dtp[row * 24 + h];
        float s = v;
#pragma unroll
        for (int o = 1; o < 64; o <<= 1) {
            float nvl = __shfl_up(s, o, 64);
            if ((tid & 63) >= o) s += nvl;
        }
        ets[tid] = __expf(Av * s);
    }
    __syncthreads();

    int t = tid >> 2, pg = tid & 3;
    float cv[16];
    float et = ets[t];
#pragma unroll
    for (int n = 0; n < 16; n++) cv[n] = bf2f(Cs3[t][n]) * et;
    size_t row = rowof(t);
    u16* yrow = yp + row * 1536 + h * 64 + pg * 16;
    u16x8 ya = *(u16x8*)yrow;
    u16x8 yb = *(u16x8*)(yrow + 8);
#pragma unroll
    for (int jj = 0; jj < 16; jj++) {
        int p = pg * 16 + jj;
        float acc = 0.f;
#pragma unroll
        for (int q = 0; q < 4; q++) {
            f32x4 hv = *(const f32x4*)&hs[p][q * 4];
            acc += cv[q*4]*hv[0] + cv[q*4+1]*hv[1] + cv[q*4+2]*hv[2] + cv[q*4+3]*hv[3];
        }
        if (jj < 8) ya[jj] = f2bf(bf2f(ya[jj]) + acc);
        else        yb[jj - 8] = f2bf(bf2f(yb[jj - 8]) + acc);
    }
    *(u16x8*)yrow = ya;
    *(u16x8*)(yrow + 8) = yb;
}

// ---------- gating + RMSnorm ----------
__global__ __launch_bounds__(256)
void gatek(const u16* __restrict__ zx0, const u16* __restrict__ zx1,
           u16* __restrict__ y0, u16* __restrict__ y1,
           const float* __restrict__ nw)
{
    int row = blockIdx.x, dir = blockIdx.y;
    const u16* zx = (dir ? zx1 : zx0) + (size_t)row * 3128;
    u16* y = (dir ? y1 : y0) + (size_t)row * 1536;
    const float* nwp = nw + dir * 1536;
    int tid = threadIdx.x;
    float g[6]; float s = 0.f;
#pragma unroll
    for (int j = 0; j < 6; j++) {
        int c = j * 256 + tid;
        float z  = bf2f(zx[c]);
        float yv = bf2f(y[c]);
        float gv = yv * z / (1.f + __expf(-z));
        g[j] = gv; s += gv * gv;
    }
    __shared__ float red[4];
    for (int o = 32; o; o >>= 1) s += __shfl_down(s, o, 64);
    if ((tid & 63) == 0) red[tid >> 6] = s;
    __syncthreads();
    s = red[0] + red[1] + red[2] + red[3];
    float sc = rsqrtf(s * (1.f / 1536.f) + 1e-5f);
#pragma unroll
    for (int j = 0; j < 6; j++) {
        int c = j * 256 + tid;
        y[c] = f2bf(g[j] * sc * nwp[c]);
    }
}

// ---------- final RMS norm ----------
__global__ __launch_bounds__(256)
void finalk(const float* __restrict__ x, const float* __restrict__ fw, float* __restrict__ out)
{
    int row = blockIdx.x; int tid = threadIdx.x;
    const float* xr = x + (size_t)row * 768;
    float v[3]; float s = 0.f;
#pragma unroll
    for (int j = 0; j < 3; j++) {
        int c = j * 256 + tid;
        v[j] = xr[c]; s += v[j] * v[j];
    }
    __shared__ float red[4];
    for (int o = 32; o; o >>= 1) s += __shfl_down(s, o, 64);
    if ((tid & 63) == 0) red[tid >> 6] = s;
    __syncthreads();
    s = red[0] + red[1] + red[2] + red[3];
    float sc = rsqrtf(s * (1.f / 768.f) + 1e-6f);
#pragma unroll
    for (int j = 0; j < 3; j++) {
        int c = j * 256 + tid;
        out[(size_t)row * 768 + c] = v[j] * sc * (1.f + fw[c]);
    }
}

// ---------- host ----------
extern "C" void kernel_launch(void* const* d_in, const int* in_sizes, int n_in,
                              void* d_out, int out_size, void* d_ws, size_t ws_size,
                              hipStream_t stream)
{
    const float* pe      = (const float*)d_in[0];
    const float* Wp      = (const float*)d_in[1];
    const float* bp      = (const float*)d_in[2];
    const float* in_w    = (const float*)d_in[3];
    const float* conv_w  = (const float*)d_in[4];
    const float* conv_b  = (const float*)d_in[5];
    const float* dt_bias = (const float*)d_in[6];
    const float* A_log   = (const float*)d_in[7];
    const float* Dh      = (const float*)d_in[8];
    const float* norm_w  = (const float*)d_in[9];
    const float* out_w   = (const float*)d_in[10];
    const float* bi_w    = (const float*)d_in[11];
    const float* ls      = (const float*)d_in[12];
    const float* fin_w   = (const float*)d_in[13];

    char* wp = (char*)d_ws;
    auto alloc = [&](size_t bytes) {
        char* r = wp; wp += (bytes + 255) & ~(size_t)255; return r;
    };
    u16*   WpT    = (u16*)  alloc((size_t)768 * 256 * 2);
    u16*   inWT   = (u16*)  alloc((size_t)4 * 3128 * 768 * 2);
    u16*   outWT  = (u16*)  alloc((size_t)4 * 768 * 1536 * 2);
    u16*   biWT   = (u16*)  alloc((size_t)2 * 768 * 1536 * 2);
    u16*   peB    = (u16*)  alloc((size_t)4096 * 256 * 2);
    float* x      = (float*)alloc((size_t)4096 * 768 * 4);
    u16*   xb     = (u16*)  alloc((size_t)4096 * 768 * 2);
    u16*   zx0    = (u16*)  alloc((size_t)4096 * 3128 * 2);
    u16*   zx1    = (u16*)  alloc((size_t)4096 * 3128 * 2);
    float* dt0    = (float*)alloc((size_t)4096 * 24 * 4);
    float* dt1    = (float*)alloc((size_t)4096 * 24 * 4);
    u16*   xc0    = (u16*)  alloc((size_t)4096 * 1568 * 2);
    u16*   xc1    = (u16*)  alloc((size_t)4096 * 1568 * 2);
    u16*   y0     = (u16*)  alloc((size_t)4096 * 1536 * 2);
    u16*   y1     = (u16*)  alloc((size_t)4096 * 1536 * 2);
    u16*   hcat   = (u16*)  alloc((size_t)4096 * 1536 * 2);
    float* states = (float*)alloc((size_t)96 * 32 * 1024 * 4);
    float* decays = (float*)alloc((size_t)96 * 32 * 4);

    // weights -> bf16 transposed
    wtransk<<<768, 256, 0, stream>>>(Wp, WpT, 256, 768);
    for (int s = 0; s < 4; s++)
        wtransk<<<(2402304 + 255) / 256, 256, 0, stream>>>(
            in_w + (size_t)s * 768 * 3128, inWT + (size_t)s * 3128 * 768, 768, 3128);
    for (int s = 0; s < 4; s++)
        wtransk<<<(1179648 + 255) / 256, 256, 0, stream>>>(
            out_w + (size_t)s * 1536 * 768, outWT + (size_t)s * 768 * 1536, 1536, 768);
    for (int s = 0; s < 2; s++)
        wtransk<<<(1179648 + 255) / 256, 256, 0, stream>>>(
            bi_w + (size_t)s * 1536 * 768, biWT + (size_t)s * 768 * 1536, 1536, 768);
    cvtk<<<4096, 256, 0, stream>>>(pe, peB, 4096 * 256);

    // patch embedding GEMM: x = peB @ Wp + bp
    gemm_k<0><<<dim3(6, 64), 256, 0, stream>>>(peB, WpT, 4096, 768, 256,
                                               x, xb, bp, nullptr, 768, 0);

    for (int i = 0; i < 2; i++) {
        for (int d = 0; d < 2; d++)
            gemm_k<1><<<dim3(25, 64), 256, 0, stream>>>(
                xb, inWT + (size_t)(i * 2 + d) * 3128 * 768, 4096, 3128, 768,
                nullptr, d ? zx1 : zx0, nullptr, nullptr, 3128, 0);
        dtk<<<(2 * 4096 * 24 + 255) / 256, 256, 0, stream>>>(zx0, zx1, dt0, dt1, dt_bias + i * 48);
        convk<<<dim3(25088, 2), 256, 0, stream>>>(zx0, zx1, xc0, xc1,
                                                  conv_w + (size_t)i * 2 * 1568 * 4,
                                                  conv_b + (size_t)i * 2 * 1568);
        scan1k<<<dim3(32, 48, 2), 256, 0, stream>>>(xc0, xc1, dt0, dt1,
                                                    A_log + i * 48, Dh + i * 48,
                                                    y0, y1, states, decays);
        scan2k<<<96, 256, 0, stream>>>(states, decays);
        scan3k<<<dim3(31, 48, 2), 256, 0, stream>>>(states, xc0, xc1, dt0, dt1,
                                                    A_log + i * 48, y0, y1);
        gatek<<<dim3(4096, 2), 256, 0, stream>>>(zx0, zx1, y0, y1, norm_w + (size_t)i * 2 * 1536);
        for (int d = 0; d < 2; d++)
            gemm_k<1><<<dim3(6, 64), 256, 0, stream>>>(
                d ? y1 : y0, outWT + (size_t)(i * 2 + d) * 768 * 1536, 4096, 768, 1536,
                nullptr, hcat, nullptr, nullptr, 1536, d * 768);
        gemm_k<2><<<dim3(6, 64), 256, 0, stream>>>(
            hcat, biWT + (size_t)i * 768 * 1536, 4096, 768, 1536,
            x, xb, nullptr, ls + i * 768, 768, 0);
    }

    finalk<<<4096, 256, 0, stream>>>(x, fin_w, (float*)d_out);
}

// Round 3
// 612.970 us; speedup vs baseline: 3.4484x; 2.1045x over previous
//
#include <hip/hip_runtime.h>

typedef unsigned short u16;
typedef short s16x8 __attribute__((ext_vector_type(8)));
typedef u16 u16x8 __attribute__((ext_vector_type(8)));
typedef float f32x4 __attribute__((ext_vector_type(4)));

// ---------- helpers ----------
__device__ inline float bf2f(u16 u) {
    union { unsigned int i; float f; } w; w.i = ((unsigned int)u) << 16; return w.f;
}
__device__ inline u16 f2bf(float f) {
    union { float f; unsigned int i; } w; w.f = f;
    unsigned int u = w.i;
    u += 0x7fffu + ((u >> 16) & 1u);
    return (u16)(u >> 16);
}

// ---------- tiled transpose + bf16: dst[n*dstride+k] = bf16(src[k*N+n]) ----------
__global__ __launch_bounds__(256)
void wtransT(const float* __restrict__ src, u16* __restrict__ dst,
             int K, int N, int dstride)
{
    __shared__ float t[32][33];
    int kt = blockIdx.y * 32, nt0 = blockIdx.x * 32;
    int lx = threadIdx.x & 31, ly = threadIdx.x >> 5;   // 32 x 8
#pragma unroll
    for (int i = 0; i < 32; i += 8) {
        int k = kt + ly + i, n = nt0 + lx;
        t[ly + i][lx] = (k < K && n < N) ? src[(size_t)k * N + n] : 0.f;
    }
    __syncthreads();
#pragma unroll
    for (int i = 0; i < 32; i += 8) {
        int n = nt0 + ly + i, k = kt + lx;
        if (n < N && k < K) dst[(size_t)n * dstride + k] = f2bf(t[lx][ly + i]);
    }
}

// ---------- plain f32 -> bf16 convert ----------
__global__ void cvtk(const float* __restrict__ src, u16* __restrict__ dst, int n) {
    int i = blockIdx.x * 256 + threadIdx.x;
    if (i < n) dst[i] = f2bf(src[i]);
}

// ---------- LDS-staged GEMM (m97 structure): C[M,N] = A[M,K] @ WT[N,K]^T ----------
// EPI 0: v += bias[col]; fout[row*ostride+col]=v; bout[same]=bf16(v)      (patch)
// EPI 1: bout[row*ostride + ocoloff + col] = bf16(v)                      (in_proj / Wcomb)
// EPI 2: xv = fout[row*768+col] + v*lsv[col]; fout=xv; bout=bf16(xv)      (fused out + residual)
template<int BM, int BN, int EPI>
__global__ __launch_bounds__(256)
void gemmL(const u16* __restrict__ A, const u16* __restrict__ WT,
           int M, int N, int K,
           float* __restrict__ fout, u16* __restrict__ bout,
           const float* __restrict__ bias, const float* __restrict__ lsv,
           int ostride, int ocoloff)
{
    constexpr int MI = BM / 32, NI = BN / 32;
    constexpr int BUF = (BM + BN) * 32;      // u16 elems per k-tile buffer
    constexpr int RA = BM / 64, RB = BN / 64;
    __shared__ u16 lds[2 * BUF];

    const int tid  = threadIdx.x;
    const int lane = tid & 63;
    const int wave = tid >> 6;
    const int wm = wave >> 1, wn = wave & 1;
    const int r16 = lane & 15;
    const int ks  = (lane >> 4) * 8;
    const int mb  = blockIdx.y * BM;
    const int nb  = blockIdx.x * BN;
    const int wbase = tid & 192;             // wave-uniform thread base

    f32x4 acc[MI][NI];
#pragma unroll
    for (int mi = 0; mi < MI; mi++)
#pragma unroll
        for (int ni = 0; ni < NI; ni++)
            acc[mi][ni] = (f32x4){0.f, 0.f, 0.f, 0.f};

    auto stage = [&](int buf, int k0) {
        u16* bufA = &lds[buf * BUF];
        u16* bufB = &lds[buf * BUF + BM * 32];
#pragma unroll
        for (int r = 0; r < RA; r++) {
            int c = r * 256 + tid;
            const u16* g = A + (size_t)(mb + (c >> 2)) * K + k0 + (c & 3) * 8;
            __builtin_amdgcn_global_load_lds(
                (const __attribute__((address_space(1))) void*)g,
                (__attribute__((address_space(3))) void*)&bufA[(r * 256 + wbase) * 8],
                16, 0, 0);
        }
#pragma unroll
        for (int r = 0; r < RB; r++) {
            int c = r * 256 + tid;
            const u16* g = WT + (size_t)(nb + (c >> 2)) * K + k0 + (c & 3) * 8;
            __builtin_amdgcn_global_load_lds(
                (const __attribute__((address_space(1))) void*)g,
                (__attribute__((address_space(3))) void*)&bufB[(r * 256 + wbase) * 8],
                16, 0, 0);
        }
    };
    auto compute = [&](int buf) {
        const u16* bufA = &lds[buf * BUF];
        const u16* bufB = &lds[buf * BUF + BM * 32];
        s16x8 af[MI], bfr[NI];
#pragma unroll
        for (int mi = 0; mi < MI; mi++)
            af[mi] = *(const s16x8*)&bufA[(wm * (BM / 2) + mi * 16 + r16) * 32 + ks];
#pragma unroll
        for (int ni = 0; ni < NI; ni++)
            bfr[ni] = *(const s16x8*)&bufB[(wn * (BN / 2) + ni * 16 + r16) * 32 + ks];
#pragma unroll
        for (int mi = 0; mi < MI; mi++)
#pragma unroll
            for (int ni = 0; ni < NI; ni++)
                acc[mi][ni] = __builtin_amdgcn_mfma_f32_16x16x32_bf16(
                    af[mi], bfr[ni], acc[mi][ni], 0, 0, 0);
    };

    const int nt = K >> 5;
    stage(0, 0);
    __syncthreads();
    for (int t = 0; t < nt; t++) {
        if (t + 1 < nt) stage((t + 1) & 1, (t + 1) << 5);
        compute(t & 1);
        __syncthreads();
    }

#pragma unroll
    for (int mi = 0; mi < MI; mi++) {
        const int rowb = mb + wm * (BM / 2) + mi * 16 + (lane >> 4) * 4;
#pragma unroll
        for (int ni = 0; ni < NI; ni++) {
            int col = nb + wn * (BN / 2) + ni * 16 + r16;
            if (col < N) {
#pragma unroll
                for (int j = 0; j < 4; j++) {
                    int row = rowb + j;
                    float v = acc[mi][ni][j];
                    if (EPI == 0) {
                        v += bias[col];
                        size_t o = (size_t)row * ostride + col;
                        fout[o] = v; bout[o] = f2bf(v);
                    } else if (EPI == 1) {
                        bout[(size_t)row * ostride + ocoloff + col] = f2bf(v);
                    } else {
                        size_t o = (size_t)row * 768 + col;
                        float xv = fout[o] + v * lsv[col];
                        fout[o] = xv; bout[o] = f2bf(xv);
                    }
                }
            }
        }
    }
}

// ---------- softplus(dt_raw + dt_bias) ----------
__global__ void dtk(const u16* __restrict__ zxAll, float* __restrict__ dtAll,
                    const float* __restrict__ dtb)
{
    int idx = blockIdx.x * 256 + threadIdx.x;
    if (idx >= 2 * 4096 * 24) return;
    int dir = idx / (4096 * 24);
    int r   = idx % (4096 * 24);
    int row = r / 24, h = r % 24;
    float raw = bf2f(zxAll[(size_t)row * 6256 + dir * 3128 + 3104 + h]) + dtb[dir * 24 + h];
    dtAll[((size_t)dir * 4096 + row) * 24 + h] = raw > 20.f ? raw : log1pf(__expf(raw));
}

// ---------- depthwise causal (dir0) / anti-causal (dir1) conv + bias + silu ----------
__global__ void convk(const u16* __restrict__ zxAll, u16* __restrict__ xcAll,
                      const float* __restrict__ cw, const float* __restrict__ cb)
{
    int dir  = blockIdx.y;
    int flat = blockIdx.x * 256 + threadIdx.x;
    int c    = flat % 1568;
    int row  = flat / 1568;
    int l    = row & 2047;
    float acc = cb[dir * 1568 + c];
    const float* w = cw + ((size_t)dir * 1568 + c) * 4;
#pragma unroll
    for (int k = 0; k < 4; k++) {
        int ll = dir ? (l + 3 - k) : (l - 3 + k);
        if (ll >= 0 && ll < 2048)
            acc += bf2f(zxAll[(size_t)(row + (ll - l)) * 6256 + dir * 3128 + 1536 + c]) * w[k];
    }
    acc = acc / (1.f + __expf(-acc));
    xcAll[((size_t)dir * 4096 + row) * 1568 + c] = f2bf(acc);
}

// ---------- chunked scan pass 1: intra-chunk (MFMA) + local chunk states ----------
__global__ __launch_bounds__(256)
void scan1k(const u16* __restrict__ xcAll, const float* __restrict__ dtAll,
            const float* __restrict__ Alog, const float* __restrict__ Dhp,
            u16* __restrict__ yAll, float* __restrict__ states, float* __restrict__ decays)
{
    const int c   = blockIdx.x;
    const int bh  = blockIdx.y;
    const int dir = blockIdx.z;
    const int b = bh / 24, h = bh % 24;
    const u16* xc    = xcAll + (size_t)dir * 4096 * 1568;
    const float* dtp = dtAll + (size_t)dir * 4096 * 24;
    u16* yp = yAll + dir * 1536;
    const float Av = -__expf(Alog[dir * 24 + h]);
    const float Dv = Dhp[dir * 24 + h];
    const int inst = (dir * 2 + b) * 24 + h;

    const int tid  = threadIdx.x;
    const int lane = tid & 63;
    const int wave = tid >> 6;
    const int r16  = lane & 15;
    const int ks   = (lane >> 4) * 8;

    __shared__ u16 xT[64][72];
    __shared__ u16 Gs[64][72];
    __shared__ u16 Bs[64][40];
    __shared__ u16 Cs[64][40];
    __shared__ u16 SBT[16][72];
    __shared__ float dts[64], cds[64];

    auto rowof = [&](int t) -> size_t {
        int i = c * 64 + t;
        int l = dir ? (2047 - i) : i;
        return (size_t)b * 2048 + l;
    };

    {
        int tr = tid >> 2;
        int pg = tid & 3;
        size_t row = rowof(tr);
        const u16* px = xc + row * 1568 + h * 64 + pg * 16;
        u16x8 v0 = *(const u16x8*)px;
        u16x8 v1 = *(const u16x8*)(px + 8);
#pragma unroll
        for (int j = 0; j < 8; j++) xT[pg * 16 + j][tr] = v0[j];
#pragma unroll
        for (int j = 0; j < 8; j++) xT[pg * 16 + 8 + j][tr] = v1[j];
    }
    {
        int t = tid & 63;
        int which = tid >> 6;
        const u16x8 z = {0,0,0,0,0,0,0,0};
        if (which == 0) {
            size_t row = rowof(t);
            const u16* pb = xc + row * 1568 + 1536;
            *(u16x8*)&Bs[t][0] = *(const u16x8*)pb;
            *(u16x8*)&Bs[t][8] = *(const u16x8*)(pb + 8);
        } else if (which == 1) {
            size_t row = rowof(t);
            const u16* pb = xc + row * 1568 + 1552;
            *(u16x8*)&Cs[t][0] = *(const u16x8*)pb;
            *(u16x8*)&Cs[t][8] = *(const u16x8*)(pb + 8);
        } else if (which == 2) {
            *(u16x8*)&Bs[t][16] = z; *(u16x8*)&Bs[t][24] = z;
        } else {
            *(u16x8*)&Cs[t][16] = z; *(u16x8*)&Cs[t][24] = z;
        }
    }
    if (tid < 64) {
        float v = dtp[rowof(tid) * 24 + h];
        dts[tid] = v;
        float s = v;
#pragma unroll
        for (int o = 1; o < 64; o <<= 1) {
            float nvl = __shfl_up(s, o, 64);
            if (lane >= o) s += nvl;
        }
        cds[tid] = s;
    }
    __syncthreads();

    {
        const s16x8 af = *(const s16x8*)&Cs[wave * 16 + r16][ks];
#pragma unroll
        for (int st = 0; st < 4; st++) {
            const s16x8 bfr = *(const s16x8*)&Bs[st * 16 + r16][ks];
            f32x4 a2 = {0.f, 0.f, 0.f, 0.f};
            a2 = __builtin_amdgcn_mfma_f32_16x16x32_bf16(af, bfr, a2, 0, 0, 0);
            int s = st * 16 + (lane & 15);
            int tbase = wave * 16 + (lane >> 4) * 4;
            float cs = cds[s], dtv = dts[s];
#pragma unroll
            for (int j = 0; j < 4; j++) {
                int t = tbase + j;
                float g = 0.f;
                if (s <= t) {
                    g = a2[j] * dtv * __expf(Av * (cds[t] - cs));
                    if (s == t) g += Dv;
                }
                Gs[t][s] = f2bf(g);
            }
        }
    }
    {
        float cdT = cds[63];
        int s = tid & 63;
        float sc = __expf(Av * (cdT - cds[s])) * dts[s];
#pragma unroll
        for (int it = 0; it < 4; it++) {
            int n = (tid >> 6) + it * 4;
            SBT[n][s] = f2bf(sc * bf2f(Bs[s][n]));
        }
    }
    __syncthreads();

    {
#pragma unroll
        for (int pt = 0; pt < 4; pt++) {
            f32x4 a2 = {0.f, 0.f, 0.f, 0.f};
#pragma unroll
            for (int kk = 0; kk < 2; kk++) {
                s16x8 af = *(const s16x8*)&Gs[wave * 16 + r16][kk * 32 + ks];
                s16x8 bfr = *(const s16x8*)&xT[pt * 16 + r16][kk * 32 + ks];
                a2 = __builtin_amdgcn_mfma_f32_16x16x32_bf16(af, bfr, a2, 0, 0, 0);
            }
            int p = pt * 16 + (lane & 15);
            int tbase = wave * 16 + (lane >> 4) * 4;
#pragma unroll
            for (int j = 0; j < 4; j++) {
                size_t row = rowof(tbase + j);
                yp[row * 3072 + h * 64 + p] = f2bf(a2[j]);
            }
        }
    }
    {
        f32x4 a2 = {0.f, 0.f, 0.f, 0.f};
#pragma unroll
        for (int kk = 0; kk < 2; kk++) {
            s16x8 af = *(const s16x8*)&xT[wave * 16 + r16][kk * 32 + ks];
            s16x8 bfr = *(const s16x8*)&SBT[r16][kk * 32 + ks];
            a2 = __builtin_amdgcn_mfma_f32_16x16x32_bf16(af, bfr, a2, 0, 0, 0);
        }
        int n = lane & 15;
        int pbase = wave * 16 + (lane >> 4) * 4;
        float* st = states + ((size_t)inst * 32 + c) * 1024;
#pragma unroll
        for (int j = 0; j < 4; j++) st[(pbase + j) * 16 + n] = a2[j];
        if (tid == 0) decays[inst * 32 + c] = __expf(Av * cds[63]);
    }
}

// ---------- chunked scan pass 2: cross-chunk recurrence ----------
__global__ __launch_bounds__(256)
void scan2k(float* __restrict__ states, const float* __restrict__ decays)
{
    int inst = blockIdx.x;
    int tid = threadIdx.x;
    float* base = states + (size_t)inst * 32 * 1024 + tid * 4;
    const float* dec = decays + inst * 32;
    f32x4 hreg = {0.f, 0.f, 0.f, 0.f};
    f32x4 L = *(f32x4*)base;
    for (int cc = 0; cc < 32; cc++) {
        f32x4 Lnext;
        if (cc + 1 < 32) Lnext = *(f32x4*)(base + (cc + 1) * 1024);
        *(f32x4*)(base + cc * 1024) = hreg;
        float d = dec[cc];
        hreg = hreg * d + L;
        L = Lnext;
    }
}

// ---------- chunked scan pass 3: y += C_t . (exp(A cd_t) h_start) ----------
__global__ __launch_bounds__(256)
void scan3k(const float* __restrict__ states,
            const u16* __restrict__ xcAll, const float* __restrict__ dtAll,
            const float* __restrict__ Alog, u16* __restrict__ yAll)
{
    const int c   = blockIdx.x + 1;
    const int bh  = blockIdx.y;
    const int dir = blockIdx.z;
    const int b = bh / 24, h = bh % 24;
    const u16* xc    = xcAll + (size_t)dir * 4096 * 1568;
    const float* dtp = dtAll + (size_t)dir * 4096 * 24;
    u16* yp = yAll + dir * 1536;
    const float Av = -__expf(Alog[dir * 24 + h]);
    const int inst = (dir * 2 + b) * 24 + h;
    const int tid = threadIdx.x;

    __shared__ float hs[64][20];
    __shared__ u16 Cs3[64][16];
    __shared__ float ets[64];

    auto rowof = [&](int t) -> size_t {
        int i = c * 64 + t;
        int l = dir ? (2047 - i) : i;
        return (size_t)b * 2048 + l;
    };

    {
        const float* sp = states + ((size_t)inst * 32 + c) * 1024 + tid * 4;
        f32x4 v = *(const f32x4*)sp;
        int e = tid * 4;
        int p = e >> 4, n = e & 15;
        hs[p][n] = v[0]; hs[p][n+1] = v[1]; hs[p][n+2] = v[2]; hs[p][n+3] = v[3];
    }
    if (tid < 64) {
        size_t row = rowof(tid);
        const u16* pc = xc + row * 1568 + 1552;
        *(u16x8*)&Cs3[tid][0] = *(const u16x8*)pc;
        *(u16x8*)&Cs3[tid][8] = *(const u16x8*)(pc + 8);
        float v = dtp[row * 24 + h];
        float s = v;
#pragma unroll
        for (int o = 1; o < 64; o <<= 1) {
            float nvl = __shfl_up(s, o, 64);
            if ((tid & 63) >= o) s += nvl;
        }
        ets[tid] = __expf(Av * s);
    }
    __syncthreads();

    int t = tid >> 2, pg = tid & 3;
    float cv[16];
    float et = ets[t];
#pragma unroll
    for (int n = 0; n < 16; n++) cv[n] = bf2f(Cs3[t][n]) * et;
    size_t row = rowof(t);
    u16* yrow = yp + row * 3072 + h * 64 + pg * 16;
    u16x8 ya = *(u16x8*)yrow;
    u16x8 yb = *(u16x8*)(yrow + 8);
#pragma unroll
    for (int jj = 0; jj < 16; jj++) {
        int p = pg * 16 + jj;
        float acc = 0.f;
#pragma unroll
        for (int q = 0; q < 4; q++) {
            f32x4 hv = *(const f32x4*)&hs[p][q * 4];
            acc += cv[q*4]*hv[0] + cv[q*4+1]*hv[1] + cv[q*4+2]*hv[2] + cv[q*4+3]*hv[3];
        }
        if (jj < 8) ya[jj] = f2bf(bf2f(ya[jj]) + acc);
        else        yb[jj - 8] = f2bf(bf2f(yb[jj - 8]) + acc);
    }
    *(u16x8*)yrow = ya;
    *(u16x8*)(yrow + 8) = yb;
}

// ---------- gating + RMSnorm ----------
__global__ __launch_bounds__(256)
void gatek(const u16* __restrict__ zxAll, u16* __restrict__ yAll,
           const float* __restrict__ nw)
{
    int row = blockIdx.x, dir = blockIdx.y;
    const u16* zx = zxAll + (size_t)row * 6256 + dir * 3128;
    u16* y = yAll + (size_t)row * 3072 + dir * 1536;
    const float* nwp = nw + dir * 1536;
    int tid = threadIdx.x;
    float g[6]; float s = 0.f;
#pragma unroll
    for (int j = 0; j < 6; j++) {
        int c = j * 256 + tid;
        float z  = bf2f(zx[c]);
        float yv = bf2f(y[c]);
        float gv = yv * z / (1.f + __expf(-z));
        g[j] = gv; s += gv * gv;
    }
    __shared__ float red[4];
    for (int o = 32; o; o >>= 1) s += __shfl_down(s, o, 64);
    if ((tid & 63) == 0) red[tid >> 6] = s;
    __syncthreads();
    s = red[0] + red[1] + red[2] + red[3];
    float sc = rsqrtf(s * (1.f / 1536.f) + 1e-5f);
#pragma unroll
    for (int j = 0; j < 6; j++) {
        int c = j * 256 + tid;
        y[c] = f2bf(g[j] * sc * nwp[c]);
    }
}

// ---------- final RMS norm ----------
__global__ __launch_bounds__(256)
void finalk(const float* __restrict__ x, const float* __restrict__ fw, float* __restrict__ out)
{
    int row = blockIdx.x; int tid = threadIdx.x;
    const float* xr = x + (size_t)row * 768;
    float v[3]; float s = 0.f;
#pragma unroll
    for (int j = 0; j < 3; j++) {
        int c = j * 256 + tid;
        v[j] = xr[c]; s += v[j] * v[j];
    }
    __shared__ float red[4];
    for (int o = 32; o; o >>= 1) s += __shfl_down(s, o, 64);
    if ((tid & 63) == 0) red[tid >> 6] = s;
    __syncthreads();
    s = red[0] + red[1] + red[2] + red[3];
    float sc = rsqrtf(s * (1.f / 768.f) + 1e-6f);
#pragma unroll
    for (int j = 0; j < 3; j++) {
        int c = j * 256 + tid;
        out[(size_t)row * 768 + c] = v[j] * sc * (1.f + fw[c]);
    }
}

// ---------- host ----------
extern "C" void kernel_launch(void* const* d_in, const int* in_sizes, int n_in,
                              void* d_out, int out_size, void* d_ws, size_t ws_size,
                              hipStream_t stream)
{
    const float* pe      = (const float*)d_in[0];
    const float* Wp      = (const float*)d_in[1];
    const float* bp      = (const float*)d_in[2];
    const float* in_w    = (const float*)d_in[3];
    const float* conv_w  = (const float*)d_in[4];
    const float* conv_b  = (const float*)d_in[5];
    const float* dt_bias = (const float*)d_in[6];
    const float* A_log   = (const float*)d_in[7];
    const float* Dh      = (const float*)d_in[8];
    const float* norm_w  = (const float*)d_in[9];
    const float* out_w   = (const float*)d_in[10];
    const float* bi_w    = (const float*)d_in[11];
    const float* ls      = (const float*)d_in[12];
    const float* fin_w   = (const float*)d_in[13];

    char* wp = (char*)d_ws;
    auto alloc = [&](size_t bytes) {
        char* r = wp; wp += (bytes + 255) & ~(size_t)255; return r;
    };
    u16*   WpT    = (u16*)  alloc((size_t)768 * 256 * 2);
    u16*   inWT   = (u16*)  alloc((size_t)2 * 6272 * 768 * 2);   // [layer][6272][768], rows 6256.. pad
    u16*   outWB  = (u16*)  alloc((size_t)4 * 1536 * 768 * 2);   // plain bf16 out_w
    u16*   biWT   = (u16*)  alloc((size_t)4 * 768 * 768 * 2);    // transposed 768x768 blocks
    u16*   WcombT = (u16*)  alloc((size_t)2 * 768 * 3072 * 2);   // [layer][768][3072]
    u16*   peB    = (u16*)  alloc((size_t)4096 * 256 * 2);
    float* x      = (float*)alloc((size_t)4096 * 768 * 4);
    u16*   xb     = (u16*)  alloc((size_t)4096 * 768 * 2);
    u16*   zxAll  = (u16*)  alloc((size_t)4096 * 6256 * 2);
    float* dtAll  = (float*)alloc((size_t)2 * 4096 * 24 * 4);
    u16*   xcAll  = (u16*)  alloc((size_t)2 * 4096 * 1568 * 2);
    u16*   yAll   = (u16*)  alloc((size_t)4096 * 3072 * 2);
    float* states = (float*)alloc((size_t)96 * 32 * 1024 * 4);
    float* decays = (float*)alloc((size_t)96 * 32 * 4);

    // ---- weight prep ----
    wtransT<<<dim3(24, 8), 256, 0, stream>>>(Wp, WpT, 256, 768, 256);
    for (int i = 0; i < 2; i++)
        for (int d = 0; d < 2; d++)
            wtransT<<<dim3(98, 24), 256, 0, stream>>>(
                in_w + (size_t)(i * 2 + d) * 768 * 3128,
                inWT + (size_t)i * 6272 * 768 + (size_t)d * 3128 * 768, 768, 3128, 768);
    for (int i = 0; i < 2; i++)
        for (int d = 0; d < 2; d++)
            wtransT<<<dim3(24, 24), 256, 0, stream>>>(
                bi_w + ((size_t)i * 1536 + d * 768) * 768,
                biWT + (size_t)(i * 2 + d) * 768 * 768, 768, 768, 768);
    cvtk<<<(4 * 1536 * 768 + 255) / 256, 256, 0, stream>>>(out_w, outWB, 4 * 1536 * 768);
    cvtk<<<4096, 256, 0, stream>>>(pe, peB, 4096 * 256);

    // ---- Wcomb[l][d] = (out_w[l,d] @ bi_w[l, d*768:(d+1)*768, :])^T, stored [n][d*1536+kk] ----
    for (int i = 0; i < 2; i++)
        for (int d = 0; d < 2; d++)
            gemmL<64, 64, 1><<<dim3(24, 12), 256, 0, stream>>>(
                biWT + (size_t)(i * 2 + d) * 768 * 768,
                outWB + (size_t)(i * 2 + d) * 1536 * 768,
                768, 1536, 768, nullptr, WcombT + (size_t)i * 768 * 3072,
                nullptr, nullptr, 3072, d * 1536);

    // ---- patch embedding GEMM ----
    gemmL<64, 64, 0><<<dim3(12, 64), 256, 0, stream>>>(
        peB, WpT, 4096, 768, 256, x, xb, bp, nullptr, 768, 0);

    for (int i = 0; i < 2; i++) {
        // merged in_proj (both dirs): N = 6256
        gemmL<128, 128, 1><<<dim3(49, 32), 256, 0, stream>>>(
            xb, inWT + (size_t)i * 6272 * 768, 4096, 6256, 768,
            nullptr, zxAll, nullptr, nullptr, 6256, 0);
        dtk<<<(2 * 4096 * 24 + 255) / 256, 256, 0, stream>>>(zxAll, dtAll, dt_bias + i * 48);
        convk<<<dim3(25088, 2), 256, 0, stream>>>(zxAll, xcAll,
                                                  conv_w + (size_t)i * 2 * 1568 * 4,
                                                  conv_b + (size_t)i * 2 * 1568);
        scan1k<<<dim3(32, 48, 2), 256, 0, stream>>>(xcAll, dtAll,
                                                    A_log + i * 48, Dh + i * 48,
                                                    yAll, states, decays);
        scan2k<<<96, 256, 0, stream>>>(states, decays);
        scan3k<<<dim3(31, 48, 2), 256, 0, stream>>>(states, xcAll, dtAll,
                                                    A_log + i * 48, yAll);
        gatek<<<dim3(4096, 2), 256, 0, stream>>>(zxAll, yAll, norm_w + (size_t)i * 2 * 1536);
        // fused out_proj + concat + bi_w + residual: x += (yAll @ Wcomb) * ls
        gemmL<64, 64, 2><<<dim3(12, 64), 256, 0, stream>>>(
            yAll, WcombT + (size_t)i * 768 * 3072, 4096, 768, 3072,
            x, xb, nullptr, ls + i * 768, 768, 0);
    }

    finalk<<<4096, 256, 0, stream>>>(x, fin_w, (float*)d_out);
}

// Round 4
// 486.379 us; speedup vs baseline: 4.3459x; 1.2603x over previous
//
#include <hip/hip_runtime.h>

typedef unsigned short u16;
typedef short s16x8 __attribute__((ext_vector_type(8)));
typedef u16 u16x8 __attribute__((ext_vector_type(8)));
typedef float f32x4 __attribute__((ext_vector_type(4)));

// ---------- helpers ----------
__device__ inline float bf2f(u16 u) {
    union { unsigned int i; float f; } w; w.i = ((unsigned int)u) << 16; return w.f;
}
__device__ inline u16 f2bf(float f) {
    union { float f; unsigned int i; } w; w.f = f;
    unsigned int u = w.i;
    u += 0x7fffu + ((u >> 16) & 1u);
    return (u16)(u >> 16);
}

// ---------- tiled transpose + bf16: dst[n*dstride+k] = bf16(src[k*N+n]) ----------
// batched over blockIdx.z: src += z*src_z; dst += (z>>1)*dz_hi + (z&1)*dz_lo
__global__ __launch_bounds__(256)
void wtransT(const float* __restrict__ src, u16* __restrict__ dst,
             int K, int N, int dstride, int src_z, int dz_hi, int dz_lo)
{
    int z = blockIdx.z;
    src += (size_t)z * src_z;
    dst += (size_t)(z >> 1) * dz_hi + (size_t)(z & 1) * dz_lo;
    __shared__ float t[32][33];
    int kt = blockIdx.y * 32, nt0 = blockIdx.x * 32;
    int lx = threadIdx.x & 31, ly = threadIdx.x >> 5;   // 32 x 8
#pragma unroll
    for (int i = 0; i < 32; i += 8) {
        int k = kt + ly + i, n = nt0 + lx;
        t[ly + i][lx] = (k < K && n < N) ? src[(size_t)k * N + n] : 0.f;
    }
    __syncthreads();
#pragma unroll
    for (int i = 0; i < 32; i += 8) {
        int n = nt0 + ly + i, k = kt + lx;
        if (n < N && k < K) dst[(size_t)n * dstride + k] = f2bf(t[lx][ly + i]);
    }
}

// ---------- plain f32 -> bf16 convert ----------
__global__ void cvtk(const float* __restrict__ src, u16* __restrict__ dst, int n) {
    int i = blockIdx.x * 256 + threadIdx.x;
    if (i < n) dst[i] = f2bf(src[i]);
}

// ---------- LDS-staged GEMM (m97 structure) + bijective XCD swizzle ----------
// C[M,N] = A[M,K] @ WT[N,K]^T
// EPI 0: v += bias[col]; fout[row*ostride+col]=v; bout[same]=bf16(v)      (patch)
// EPI 1: bout[row*ostride + ocoloff + col] = bf16(v)                      (in_proj / Wcomb)
// EPI 2: xv = fout[row*768+col] + v*lsv[col]; fout=xv; bout=bf16(xv)      (fused out + residual)
// batched (Wcomb): A += z*aZ; WT += z*wZ; bout += (z>>1)*oZ; ocoloff += (z&1)*ocolZ
template<int BM, int BN, int EPI>
__global__ __launch_bounds__(256)
void gemmL(const u16* __restrict__ A, const u16* __restrict__ WT,
           int M, int N, int K,
           float* __restrict__ fout, u16* __restrict__ bout,
           const float* __restrict__ bias, const float* __restrict__ lsv,
           int ostride, int ocoloff,
           size_t aZ, size_t wZ, size_t oZ, int ocolZ)
{
    constexpr int MI = BM / 32, NI = BN / 32;
    constexpr int BUF = (BM + BN) * 32;      // u16 elems per k-tile buffer
    constexpr int RA = BM / 64, RB = BN / 64;
    __shared__ u16 lds[2 * BUF];

    {
        int z = blockIdx.z;
        A += (size_t)z * aZ; WT += (size_t)z * wZ;
        bout += (size_t)(z >> 1) * oZ; ocoloff += (z & 1) * ocolZ;
    }

    // bijective XCD swizzle (m204): each XCD gets a contiguous wid chunk;
    // wid m-fastest so consecutive wids share the B-panel (same n-tile).
    int mt, nt;
    {
        int nwg = gridDim.x * gridDim.y;
        int f = blockIdx.y * gridDim.x + blockIdx.x;
        int q = nwg >> 3, r = nwg & 7;
        int xcd = f & 7, lo = f >> 3;
        int wid = (xcd < r ? xcd * (q + 1) : r * (q + 1) + (xcd - r) * q) + lo;
        mt = wid % gridDim.y; nt = wid / gridDim.y;
    }

    const int tid  = threadIdx.x;
    const int lane = tid & 63;
    const int wave = tid >> 6;
    const int wm = wave >> 1, wn = wave & 1;
    const int r16 = lane & 15;
    const int ks  = (lane >> 4) * 8;
    const int mb  = mt * BM;
    const int nb  = nt * BN;
    const int wbase = tid & 192;             // wave-uniform thread base

    f32x4 acc[MI][NI];
#pragma unroll
    for (int mi = 0; mi < MI; mi++)
#pragma unroll
        for (int ni = 0; ni < NI; ni++)
            acc[mi][ni] = (f32x4){0.f, 0.f, 0.f, 0.f};

    auto stage = [&](int buf, int k0) {
        u16* bufA = &lds[buf * BUF];
        u16* bufB = &lds[buf * BUF + BM * 32];
#pragma unroll
        for (int r = 0; r < RA; r++) {
            int c = r * 256 + tid;
            const u16* g = A + (size_t)(mb + (c >> 2)) * K + k0 + (c & 3) * 8;
            __builtin_amdgcn_global_load_lds(
                (const __attribute__((address_space(1))) void*)g,
                (__attribute__((address_space(3))) void*)&bufA[(r * 256 + wbase) * 8],
                16, 0, 0);
        }
#pragma unroll
        for (int r = 0; r < RB; r++) {
            int c = r * 256 + tid;
            const u16* g = WT + (size_t)(nb + (c >> 2)) * K + k0 + (c & 3) * 8;
            __builtin_amdgcn_global_load_lds(
                (const __attribute__((address_space(1))) void*)g,
                (__attribute__((address_space(3))) void*)&bufB[(r * 256 + wbase) * 8],
                16, 0, 0);
        }
    };
    auto compute = [&](int buf) {
        const u16* bufA = &lds[buf * BUF];
        const u16* bufB = &lds[buf * BUF + BM * 32];
        s16x8 af[MI], bfr[NI];
#pragma unroll
        for (int mi = 0; mi < MI; mi++)
            af[mi] = *(const s16x8*)&bufA[(wm * (BM / 2) + mi * 16 + r16) * 32 + ks];
#pragma unroll
        for (int ni = 0; ni < NI; ni++)
            bfr[ni] = *(const s16x8*)&bufB[(wn * (BN / 2) + ni * 16 + r16) * 32 + ks];
#pragma unroll
        for (int mi = 0; mi < MI; mi++)
#pragma unroll
            for (int ni = 0; ni < NI; ni++)
                acc[mi][ni] = __builtin_amdgcn_mfma_f32_16x16x32_bf16(
                    af[mi], bfr[ni], acc[mi][ni], 0, 0, 0);
    };

    const int nt2 = K >> 5;
    stage(0, 0);
    __syncthreads();
    for (int t = 0; t < nt2; t++) {
        if (t + 1 < nt2) stage((t + 1) & 1, (t + 1) << 5);
        compute(t & 1);
        __syncthreads();
    }

#pragma unroll
    for (int mi = 0; mi < MI; mi++) {
        const int rowb = mb + wm * (BM / 2) + mi * 16 + (lane >> 4) * 4;
#pragma unroll
        for (int ni = 0; ni < NI; ni++) {
            int col = nb + wn * (BN / 2) + ni * 16 + r16;
            if (col < N) {
#pragma unroll
                for (int j = 0; j < 4; j++) {
                    int row = rowb + j;
                    float v = acc[mi][ni][j];
                    if (EPI == 0) {
                        v += bias[col];
                        size_t o = (size_t)row * ostride + col;
                        fout[o] = v; bout[o] = f2bf(v);
                    } else if (EPI == 1) {
                        bout[(size_t)row * ostride + ocoloff + col] = f2bf(v);
                    } else {
                        size_t o = (size_t)row * 768 + col;
                        float xv = fout[o] + v * lsv[col];
                        fout[o] = xv; bout[o] = f2bf(xv);
                    }
                }
            }
        }
    }
}

// ---------- softplus(dt_raw + dt_bias) ----------
__global__ void dtk(const u16* __restrict__ zxAll, float* __restrict__ dtAll,
                    const float* __restrict__ dtb)
{
    int idx = blockIdx.x * 256 + threadIdx.x;
    if (idx >= 2 * 4096 * 24) return;
    int dir = idx / (4096 * 24);
    int r   = idx % (4096 * 24);
    int row = r / 24, h = r % 24;
    float raw = bf2f(zxAll[(size_t)row * 6256 + dir * 3128 + 3104 + h]) + dtb[dir * 24 + h];
    dtAll[((size_t)dir * 4096 + row) * 24 + h] = raw > 20.f ? raw : log1pf(__expf(raw));
}

// ---------- chunked scan pass 1 (conv+silu fused) ----------
// grid (32 chunks, 48 b*h, 2 dir), 256 threads
__global__ __launch_bounds__(256)
void scan1k(const u16* __restrict__ zxAll, const float* __restrict__ dtAll,
            const float* __restrict__ cw, const float* __restrict__ cb,
            const float* __restrict__ Alog, const float* __restrict__ Dhp,
            u16* __restrict__ yAll, float* __restrict__ states, float* __restrict__ decays)
{
    const int c   = blockIdx.x;
    const int bh  = blockIdx.y;
    const int dir = blockIdx.z;
    const int b = bh / 24, h = bh % 24;
    const float* dtp = dtAll + (size_t)dir * 4096 * 24;
    u16* yp = yAll + dir * 1536;
    const float Av = -__expf(Alog[dir * 24 + h]);
    const float Dv = Dhp[dir * 24 + h];
    const int inst = (dir * 2 + b) * 24 + h;

    const int tid  = threadIdx.x;
    const int lane = tid & 63;
    const int wave = tid >> 6;
    const int r16  = lane & 15;
    const int ks   = (lane >> 4) * 8;

    __shared__ u16 xT[64][72];
    __shared__ u16 Gs[64][72];
    __shared__ u16 Bs[64][40];
    __shared__ u16 Cs[64][40];
    __shared__ u16 SBT[16][72];
    __shared__ float dts[64], cds[64];

    const u16* zxd = zxAll + dir * 3128 + 1536;  // xBC channel base
    auto growp = [&](int ii) -> const u16* {     // row ptr for flipped-coord ii
        int l = dir ? (2047 - ii) : ii;
        return zxd + ((size_t)b * 2048 + l) * 6256;
    };
    auto rowof = [&](int t) -> size_t {
        int i = c * 64 + t;
        int l = dir ? (2047 - i) : i;
        return (size_t)b * 2048 + l;
    };
    const u16x8 zz = {0,0,0,0,0,0,0,0};

    // ---- x-part: depthwise conv + silu -> xT (transposed) ----
    {
        int tr = tid >> 2, pg = tid & 3;
        int chb = h * 64 + pg * 16;             // xBC channel
        int i0 = c * 64 + tr;
        u16x8 tv[4][2];
#pragma unroll
        for (int k = 0; k < 4; k++) {
            int ii = i0 - 3 + k;
            if (ii >= 0) {
                const u16* s = growp(ii) + chb;
                tv[k][0] = *(const u16x8*)s;
                tv[k][1] = *(const u16x8*)(s + 8);
            } else { tv[k][0] = zz; tv[k][1] = zz; }
        }
        const float* cwp = cw + ((size_t)dir * 1568 + chb) * 4;
        const float* cbp = cb + (size_t)dir * 1568 + chb;
#pragma unroll
        for (int j = 0; j < 16; j++) {
            f32x4 wj = *(const f32x4*)(cwp + j * 4);
            float a = cbp[j];
            int hi = j >> 3, lo2 = j & 7;
            a += bf2f(tv[0][hi][lo2]) * wj[0] + bf2f(tv[1][hi][lo2]) * wj[1]
               + bf2f(tv[2][hi][lo2]) * wj[2] + bf2f(tv[3][hi][lo2]) * wj[3];
            a = a / (1.f + __expf(-a));
            xT[pg * 16 + j][tr] = f2bf(a);
        }
    }
    // ---- B/C: conv + silu; pads zeroed ----
    {
        int t = tid & 63, which = tid >> 6;
        if (which < 2) {
            int chb = 1536 + which * 16;        // B: 1536..1551, C: 1552..1567
            int i0 = c * 64 + t;
            u16x8 tv[4][2];
#pragma unroll
            for (int k = 0; k < 4; k++) {
                int ii = i0 - 3 + k;
                if (ii >= 0) {
                    const u16* s = growp(ii) + chb;
                    tv[k][0] = *(const u16x8*)s;
                    tv[k][1] = *(const u16x8*)(s + 8);
                } else { tv[k][0] = zz; tv[k][1] = zz; }
            }
            const float* cwp = cw + ((size_t)dir * 1568 + chb) * 4;
            const float* cbp = cb + (size_t)dir * 1568 + chb;
            u16* dst = which ? &Cs[t][0] : &Bs[t][0];
#pragma unroll
            for (int j = 0; j < 16; j++) {
                f32x4 wj = *(const f32x4*)(cwp + j * 4);
                float a = cbp[j];
                int hi = j >> 3, lo2 = j & 7;
                a += bf2f(tv[0][hi][lo2]) * wj[0] + bf2f(tv[1][hi][lo2]) * wj[1]
                   + bf2f(tv[2][hi][lo2]) * wj[2] + bf2f(tv[3][hi][lo2]) * wj[3];
                a = a / (1.f + __expf(-a));
                dst[j] = f2bf(a);
            }
        } else {
            u16* dst = (which == 2) ? &Bs[t][16] : &Cs[t][16];
            *(u16x8*)dst = zz; *(u16x8*)(dst + 8) = zz;
        }
    }
    // ---- dt + inclusive cumsum (wave 0) ----
    if (tid < 64) {
        float v = dtp[rowof(tid) * 24 + h];
        dts[tid] = v;
        float s = v;
#pragma unroll
        for (int o = 1; o < 64; o <<= 1) {
            float nvl = __shfl_up(s, o, 64);
            if (lane >= o) s += nvl;
        }
        cds[tid] = s;
    }
    __syncthreads();

    // ---- Gram S = C B^T -> mask/decay-scale -> G (bf16, D on diagonal) ----
    {
        const s16x8 af = *(const s16x8*)&Cs[wave * 16 + r16][ks];
#pragma unroll
        for (int st = 0; st < 4; st++) {
            const s16x8 bfr = *(const s16x8*)&Bs[st * 16 + r16][ks];
            f32x4 a2 = {0.f, 0.f, 0.f, 0.f};
            a2 = __builtin_amdgcn_mfma_f32_16x16x32_bf16(af, bfr, a2, 0, 0, 0);
            int s = st * 16 + (lane & 15);
            int tbase = wave * 16 + (lane >> 4) * 4;
            float cs = cds[s], dtv = dts[s];
#pragma unroll
            for (int j = 0; j < 4; j++) {
                int t = tbase + j;
                float g = 0.f;
                if (s <= t) {
                    g = a2[j] * dtv * __expf(Av * (cds[t] - cs));
                    if (s == t) g += Dv;
                }
                Gs[t][s] = f2bf(g);
            }
        }
    }
    // ---- decay-scaled B^T for local state ----
    {
        float cdT = cds[63];
        int s = tid & 63;
        float sc = __expf(Av * (cdT - cds[s])) * dts[s];
#pragma unroll
        for (int it = 0; it < 4; it++) {
            int n = (tid >> 6) + it * 4;
            SBT[n][s] = f2bf(sc * bf2f(Bs[s][n]));
        }
    }
    __syncthreads();

    // ---- y_local = G @ x ----
    {
#pragma unroll
        for (int pt = 0; pt < 4; pt++) {
            f32x4 a2 = {0.f, 0.f, 0.f, 0.f};
#pragma unroll
            for (int kk = 0; kk < 2; kk++) {
                s16x8 af = *(const s16x8*)&Gs[wave * 16 + r16][kk * 32 + ks];
                s16x8 bfr = *(const s16x8*)&xT[pt * 16 + r16][kk * 32 + ks];
                a2 = __builtin_amdgcn_mfma_f32_16x16x32_bf16(af, bfr, a2, 0, 0, 0);
            }
            int p = pt * 16 + (lane & 15);
            int tbase = wave * 16 + (lane >> 4) * 4;
#pragma unroll
            for (int j = 0; j < 4; j++) {
                size_t row = rowof(tbase + j);
                yp[row * 3072 + h * 64 + p] = f2bf(a2[j]);
            }
        }
    }
    // ---- local chunk state L = x^T @ SB ----
    {
        f32x4 a2 = {0.f, 0.f, 0.f, 0.f};
#pragma unroll
        for (int kk = 0; kk < 2; kk++) {
            s16x8 af = *(const s16x8*)&xT[wave * 16 + r16][kk * 32 + ks];
            s16x8 bfr = *(const s16x8*)&SBT[r16][kk * 32 + ks];
            a2 = __builtin_amdgcn_mfma_f32_16x16x32_bf16(af, bfr, a2, 0, 0, 0);
        }
        int n = lane & 15;
        int pbase = wave * 16 + (lane >> 4) * 4;
        float* st = states + ((size_t)inst * 32 + c) * 1024;
#pragma unroll
        for (int j = 0; j < 4; j++) st[(pbase + j) * 16 + n] = a2[j];
        if (tid == 0) decays[inst * 32 + c] = __expf(Av * cds[63]);
    }
}

// ---------- chunked scan pass 2: cross-chunk recurrence ----------
__global__ __launch_bounds__(256)
void scan2k(float* __restrict__ states, const float* __restrict__ decays)
{
    int inst = blockIdx.x;
    int tid = threadIdx.x;
    float* base = states + (size_t)inst * 32 * 1024 + tid * 4;
    const float* dec = decays + inst * 32;
    f32x4 hreg = {0.f, 0.f, 0.f, 0.f};
    f32x4 L = *(f32x4*)base;
    for (int cc = 0; cc < 32; cc++) {
        f32x4 Lnext;
        if (cc + 1 < 32) Lnext = *(f32x4*)(base + (cc + 1) * 1024);
        *(f32x4*)(base + cc * 1024) = hreg;
        float d = dec[cc];
        hreg = hreg * d + L;
        L = Lnext;
    }
}

// ---------- chunked scan pass 3: y += C_t . (exp(A cd_t) h_start), conv fused ----------
__global__ __launch_bounds__(256)
void scan3k(const float* __restrict__ states,
            const u16* __restrict__ zxAll, const float* __restrict__ dtAll,
            const float* __restrict__ cw, const float* __restrict__ cb,
            const float* __restrict__ Alog, u16* __restrict__ yAll)
{
    const int c   = blockIdx.x + 1;
    const int bh  = blockIdx.y;
    const int dir = blockIdx.z;
    const int b = bh / 24, h = bh % 24;
    const float* dtp = dtAll + (size_t)dir * 4096 * 24;
    u16* yp = yAll + dir * 1536;
    const float Av = -__expf(Alog[dir * 24 + h]);
    const int inst = (dir * 2 + b) * 24 + h;
    const int tid = threadIdx.x;

    __shared__ float hs[64][20];
    __shared__ u16 Cs3[64][16];
    __shared__ float ets[64];

    const u16* zxd = zxAll + dir * 3128 + 1536;
    auto growp = [&](int ii) -> const u16* {
        int l = dir ? (2047 - ii) : ii;
        return zxd + ((size_t)b * 2048 + l) * 6256;
    };
    auto rowof = [&](int t) -> size_t {
        int i = c * 64 + t;
        int l = dir ? (2047 - i) : i;
        return (size_t)b * 2048 + l;
    };

    {
        const float* sp = states + ((size_t)inst * 32 + c) * 1024 + tid * 4;
        f32x4 v = *(const f32x4*)sp;
        int e = tid * 4;
        int p = e >> 4, n = e & 15;
        hs[p][n] = v[0]; hs[p][n+1] = v[1]; hs[p][n+2] = v[2]; hs[p][n+3] = v[3];
    }
    if (tid < 64) {
        // conv+silu for C channels (1552..1567); c>=1 so all taps in-range
        int i0 = c * 64 + tid;
        u16x8 tv[4][2];
#pragma unroll
        for (int k = 0; k < 4; k++) {
            const u16* s = growp(i0 - 3 + k) + 1552;
            tv[k][0] = *(const u16x8*)s;
            tv[k][1] = *(const u16x8*)(s + 8);
        }
        const float* cwp = cw + ((size_t)dir * 1568 + 1552) * 4;
        const float* cbp = cb + (size_t)dir * 1568 + 1552;
#pragma unroll
        for (int j = 0; j < 16; j++) {
            f32x4 wj = *(const f32x4*)(cwp + j * 4);
            float a = cbp[j];
            int hi = j >> 3, lo2 = j & 7;
            a += bf2f(tv[0][hi][lo2]) * wj[0] + bf2f(tv[1][hi][lo2]) * wj[1]
               + bf2f(tv[2][hi][lo2]) * wj[2] + bf2f(tv[3][hi][lo2]) * wj[3];
            a = a / (1.f + __expf(-a));
            Cs3[tid][j] = f2bf(a);
        }
        float v = dtp[rowof(tid) * 24 + h];
        float s = v;
#pragma unroll
        for (int o = 1; o < 64; o <<= 1) {
            float nvl = __shfl_up(s, o, 64);
            if ((tid & 63) >= o) s += nvl;
        }
        ets[tid] = __expf(Av * s);
    }
    __syncthreads();

    int t = tid >> 2, pg = tid & 3;
    float cv[16];
    float et = ets[t];
#pragma unroll
    for (int n = 0; n < 16; n++) cv[n] = bf2f(Cs3[t][n]) * et;
    size_t row = rowof(t);
    u16* yrow = yp + row * 3072 + h * 64 + pg * 16;
    u16x8 ya = *(u16x8*)yrow;
    u16x8 yb = *(u16x8*)(yrow + 8);
#pragma unroll
    for (int jj = 0; jj < 16; jj++) {
        int p = pg * 16 + jj;
        float acc = 0.f;
#pragma unroll
        for (int q = 0; q < 4; q++) {
            f32x4 hv = *(const f32x4*)&hs[p][q * 4];
            acc += cv[q*4]*hv[0] + cv[q*4+1]*hv[1] + cv[q*4+2]*hv[2] + cv[q*4+3]*hv[3];
        }
        if (jj < 8) ya[jj] = f2bf(bf2f(ya[jj]) + acc);
        else        yb[jj - 8] = f2bf(bf2f(yb[jj - 8]) + acc);
    }
    *(u16x8*)yrow = ya;
    *(u16x8*)(yrow + 8) = yb;
}

// ---------- gating + RMSnorm ----------
__global__ __launch_bounds__(256)
void gatek(const u16* __restrict__ zxAll, u16* __restrict__ yAll,
           const float* __restrict__ nw)
{
    int row = blockIdx.x, dir = blockIdx.y;
    const u16* zx = zxAll + (size_t)row * 6256 + dir * 3128;
    u16* y = yAll + (size_t)row * 3072 + dir * 1536;
    const float* nwp = nw + dir * 1536;
    int tid = threadIdx.x;
    float g[6]; float s = 0.f;
#pragma unroll
    for (int j = 0; j < 6; j++) {
        int c = j * 256 + tid;
        float z  = bf2f(zx[c]);
        float yv = bf2f(y[c]);
        float gv = yv * z / (1.f + __expf(-z));
        g[j] = gv; s += gv * gv;
    }
    __shared__ float red[4];
    for (int o = 32; o; o >>= 1) s += __shfl_down(s, o, 64);
    if ((tid & 63) == 0) red[tid >> 6] = s;
    __syncthreads();
    s = red[0] + red[1] + red[2] + red[3];
    float sc = rsqrtf(s * (1.f / 1536.f) + 1e-5f);
#pragma unroll
    for (int j = 0; j < 6; j++) {
        int c = j * 256 + tid;
        y[c] = f2bf(g[j] * sc * nwp[c]);
    }
}

// ---------- final RMS norm ----------
__global__ __launch_bounds__(256)
void finalk(const float* __restrict__ x, const float* __restrict__ fw, float* __restrict__ out)
{
    int row = blockIdx.x; int tid = threadIdx.x;
    const float* xr = x + (size_t)row * 768;
    float v[3]; float s = 0.f;
#pragma unroll
    for (int j = 0; j < 3; j++) {
        int c = j * 256 + tid;
        v[j] = xr[c]; s += v[j] * v[j];
    }
    __shared__ float red[4];
    for (int o = 32; o; o >>= 1) s += __shfl_down(s, o, 64);
    if ((tid & 63) == 0) red[tid >> 6] = s;
    __syncthreads();
    s = red[0] + red[1] + red[2] + red[3];
    float sc = rsqrtf(s * (1.f / 768.f) + 1e-6f);
#pragma unroll
    for (int j = 0; j < 3; j++) {
        int c = j * 256 + tid;
        out[(size_t)row * 768 + c] = v[j] * sc * (1.f + fw[c]);
    }
}

// ---------- host ----------
extern "C" void kernel_launch(void* const* d_in, const int* in_sizes, int n_in,
                              void* d_out, int out_size, void* d_ws, size_t ws_size,
                              hipStream_t stream)
{
    const float* pe      = (const float*)d_in[0];
    const float* Wp      = (const float*)d_in[1];
    const float* bp      = (const float*)d_in[2];
    const float* in_w    = (const float*)d_in[3];
    const float* conv_w  = (const float*)d_in[4];
    const float* conv_b  = (const float*)d_in[5];
    const float* dt_bias = (const float*)d_in[6];
    const float* A_log   = (const float*)d_in[7];
    const float* Dh      = (const float*)d_in[8];
    const float* norm_w  = (const float*)d_in[9];
    const float* out_w   = (const float*)d_in[10];
    const float* bi_w    = (const float*)d_in[11];
    const float* ls      = (const float*)d_in[12];
    const float* fin_w   = (const float*)d_in[13];

    char* wp = (char*)d_ws;
    auto alloc = [&](size_t bytes) {
        char* r = wp; wp += (bytes + 255) & ~(size_t)255; return r;
    };
    u16*   WpT    = (u16*)  alloc((size_t)768 * 256 * 2);
    u16*   inWT   = (u16*)  alloc((size_t)2 * 6272 * 768 * 2);   // [layer][6272][768]
    u16*   outWB  = (u16*)  alloc((size_t)4 * 1536 * 768 * 2);   // plain bf16 out_w
    u16*   biWT   = (u16*)  alloc((size_t)4 * 768 * 768 * 2);    // transposed 768x768 blocks
    u16*   WcombT = (u16*)  alloc((size_t)2 * 768 * 3072 * 2);   // [layer][768][3072]
    u16*   peB    = (u16*)  alloc((size_t)4096 * 256 * 2);
    float* x      = (float*)alloc((size_t)4096 * 768 * 4);
    u16*   xb     = (u16*)  alloc((size_t)4096 * 768 * 2);
    u16*   zxAll  = (u16*)  alloc((size_t)4096 * 6256 * 2);
    float* dtAll  = (float*)alloc((size_t)2 * 4096 * 24 * 4);
    u16*   yAll   = (u16*)  alloc((size_t)4096 * 3072 * 2);
    float* states = (float*)alloc((size_t)96 * 32 * 1024 * 4);
    float* decays = (float*)alloc((size_t)96 * 32 * 4);

    // ---- weight prep (batched over z) ----
    wtransT<<<dim3(24, 8, 1), 256, 0, stream>>>(Wp, WpT, 256, 768, 256, 0, 0, 0);
    wtransT<<<dim3(98, 24, 4), 256, 0, stream>>>(in_w, inWT, 768, 3128, 768,
                                                 2402304, 4816896, 2402304);
    wtransT<<<dim3(24, 24, 4), 256, 0, stream>>>(bi_w, biWT, 768, 768, 768,
                                                 589824, 1179648, 589824);
    cvtk<<<(4 * 1536 * 768 + 255) / 256, 256, 0, stream>>>(out_w, outWB, 4 * 1536 * 768);
    cvtk<<<4096, 256, 0, stream>>>(pe, peB, 4096 * 256);

    // ---- Wcomb[z=i*2+d] = (bi_w[i,d-block]^T) @ out_w[i,d]^T, batched ----
    gemmL<64, 64, 1><<<dim3(24, 12, 4), 256, 0, stream>>>(
        biWT, outWB, 768, 1536, 768, nullptr, WcombT,
        nullptr, nullptr, 3072, 0,
        (size_t)589824, (size_t)1179648, (size_t)768 * 3072, 1536);

    // ---- patch embedding GEMM ----
    gemmL<64, 64, 0><<<dim3(12, 64, 1), 256, 0, stream>>>(
        peB, WpT, 4096, 768, 256, x, xb, bp, nullptr, 768, 0, 0, 0, 0, 0);

    for (int i = 0; i < 2; i++) {
        // merged in_proj (both dirs): N = 6256
        gemmL<128, 128, 1><<<dim3(49, 32, 1), 256, 0, stream>>>(
            xb, inWT + (size_t)i * 6272 * 768, 4096, 6256, 768,
            nullptr, zxAll, nullptr, nullptr, 6256, 0, 0, 0, 0, 0);
        dtk<<<(2 * 4096 * 24 + 255) / 256, 256, 0, stream>>>(zxAll, dtAll, dt_bias + i * 48);
        scan1k<<<dim3(32, 48, 2), 256, 0, stream>>>(zxAll, dtAll,
                                                    conv_w + (size_t)i * 2 * 1568 * 4,
                                                    conv_b + (size_t)i * 2 * 1568,
                                                    A_log + i * 48, Dh + i * 48,
                                                    yAll, states, decays);
        scan2k<<<96, 256, 0, stream>>>(states, decays);
        scan3k<<<dim3(31, 48, 2), 256, 0, stream>>>(states, zxAll, dtAll,
                                                    conv_w + (size_t)i * 2 * 1568 * 4,
                                                    conv_b + (size_t)i * 2 * 1568,
                                                    A_log + i * 48, yAll);
        gatek<<<dim3(4096, 2), 256, 0, stream>>>(zxAll, yAll, norm_w + (size_t)i * 2 * 1536);
        // fused out_proj + concat + bi_w + residual: x += (yAll @ Wcomb) * ls
        gemmL<128, 64, 2><<<dim3(12, 32, 1), 256, 0, stream>>>(
            yAll, WcombT + (size_t)i * 768 * 3072, 4096, 768, 3072,
            x, xb, nullptr, ls + i * 768, 768, 0, 0, 0, 0, 0);
    }

    finalk<<<4096, 256, 0, stream>>>(x, fin_w, (float*)d_out);
}